// Round 1
// baseline (628.459 us; speedup 1.0000x reference)
//
#include <hip/hip_runtime.h>
#include <cstdint>
#include <cstddef>

#define IN_CH 128
#define HID_CH 128
#define OUT_CH 64

// ---------------- CSR build ----------------

__global__ void count_deg(const int* __restrict__ dst, int* __restrict__ deg, int E) {
    int e = blockIdx.x * 256 + threadIdx.x;
    if (e < E) atomicAdd(&deg[dst[e]], 1);
}

__global__ void scan1(const int* __restrict__ deg, int* __restrict__ rowptr,
                      int* __restrict__ bsum, int n) {
    __shared__ int s[256];
    int t = threadIdx.x;
    int i = blockIdx.x * 256 + t;
    int v = (i < n) ? deg[i] : 0;
    s[t] = v;
    __syncthreads();
    for (int o = 1; o < 256; o <<= 1) {
        int add = (t >= o) ? s[t - o] : 0;
        __syncthreads();
        s[t] += add;
        __syncthreads();
    }
    if (i < n) rowptr[i] = s[t] - v;        // exclusive within block
    if (t == 255) bsum[blockIdx.x] = s[255];
}

__global__ void scan2(const int* __restrict__ bsum, int* __restrict__ boff, int nb) {
    __shared__ int s[512];
    int t = threadIdx.x;
    int v = (t < nb) ? bsum[t] : 0;
    s[t] = v;
    __syncthreads();
    for (int o = 1; o < 512; o <<= 1) {
        int add = (t >= o) ? s[t - o] : 0;
        __syncthreads();
        s[t] += add;
        __syncthreads();
    }
    if (t < nb) boff[t] = s[t] - v;         // exclusive block offsets
}

__global__ void scan3(int* __restrict__ rowptr, const int* __restrict__ boff,
                      int* __restrict__ cursor, int n) {
    int i = blockIdx.x * 256 + threadIdx.x;
    if (i < n) {
        int v = rowptr[i] + boff[blockIdx.x];
        rowptr[i] = v;
        cursor[i] = v;
    }
}

__global__ void dinv_k(const int* __restrict__ deg, float* __restrict__ dinv, int n) {
    int i = blockIdx.x * 256 + threadIdx.x;
    if (i < n) dinv[i] = rsqrtf((float)(deg[i] + 2));  // +2 self-loops
}

__global__ void fill_csr(const int* __restrict__ src, const int* __restrict__ dst,
                         int* __restrict__ cursor, int* __restrict__ csr, int E) {
    int e = blockIdx.x * 256 + threadIdx.x;
    if (e < E) {
        int d = dst[e];
        int p = atomicAdd(&cursor[d], 1);
        csr[p] = src[e];
    }
}

// ---------------- GEMM (K = 128 fixed) ----------------
// C[n, OUT] = A[n, 128] @ W[128, OUT].  Tile: 128 rows x OUT cols per block,
// 256 threads, thread micro-tile = (128/RG) rows x 8 cols, rows strided by RG
// so a-reads within a wave land on distinct LDS banks.

template <int OUT, int RG>
__global__ __launch_bounds__(256) void gemm_k128(const float* __restrict__ A,
                                                 const float* __restrict__ W,
                                                 float* __restrict__ C, int n) {
    constexpr int K = 128, KT = 32, ROWS = 128;
    constexpr int CG = 256 / RG;   // col groups
    constexpr int TC = OUT / CG;   // cols per thread (= 8)
    constexpr int TR = ROWS / RG;  // rows per thread (8 or 4)
    static_assert(TC == 8, "layout assumes 8 cols/thread");

    __shared__ float As[ROWS][KT + 4];
    __shared__ float Ws[KT][OUT];

    const int t = threadIdx.x;
    const int row0 = blockIdx.x * ROWS;
    const int cg = t % CG, rg = t / CG;
    const int c0 = cg * TC;

    float acc[TR][TC];
    for (int i = 0; i < TR; i++)
        for (int j = 0; j < TC; j++) acc[i][j] = 0.f;

    for (int kt = 0; kt < K; kt += KT) {
        // stage A chunk: ROWS x KT
        for (int i = t; i < ROWS * KT / 4; i += 256) {
            int r = i / (KT / 4), kc = i % (KT / 4);
            float4 vv = make_float4(0.f, 0.f, 0.f, 0.f);
            if (row0 + r < n)
                vv = *(const float4*)(A + (size_t)(row0 + r) * K + kt + kc * 4);
            *(float4*)&As[r][kc * 4] = vv;
        }
        // stage W chunk: KT x OUT (contiguous rows)
        for (int i = t; i < KT * OUT / 4; i += 256)
            ((float4*)&Ws[0][0])[i] = ((const float4*)(W + (size_t)kt * OUT))[i];
        __syncthreads();

        for (int k = 0; k < KT; k += 4) {
            float4 a[TR];
#pragma unroll
            for (int i = 0; i < TR; i++) a[i] = *(const float4*)&As[rg + i * RG][k];
#pragma unroll
            for (int kk = 0; kk < 4; kk++) {
                float4 b0 = *(const float4*)&Ws[k + kk][c0];
                float4 b1 = *(const float4*)&Ws[k + kk][c0 + 4];
#pragma unroll
                for (int i = 0; i < TR; i++) {
                    float av = (&a[i].x)[kk];
                    acc[i][0] += av * b0.x; acc[i][1] += av * b0.y;
                    acc[i][2] += av * b0.z; acc[i][3] += av * b0.w;
                    acc[i][4] += av * b1.x; acc[i][5] += av * b1.y;
                    acc[i][6] += av * b1.z; acc[i][7] += av * b1.w;
                }
            }
        }
        __syncthreads();
    }

    for (int i = 0; i < TR; i++) {
        int r = row0 + rg + i * RG;
        if (r < n) {
            float* cp = C + (size_t)r * OUT + c0;
            *(float4*)cp = make_float4(acc[i][0], acc[i][1], acc[i][2], acc[i][3]);
            *(float4*)(cp + 4) = make_float4(acc[i][4], acc[i][5], acc[i][6], acc[i][7]);
        }
    }
}

// ---------------- Aggregation (one wave per node) ----------------
// out[v] = dinv[v] * sum_{u in N(v)} dinv[u]*H[u] + 2*dinv[v]^2*H[v] + bias
// layer1: + ReLU.  layer2: + log_softmax over 64 channels.

__global__ __launch_bounds__(256) void agg_relu_128(
    const float* __restrict__ H, const int* __restrict__ csr,
    const int* __restrict__ rowptr, const int* __restrict__ deg,
    const float* __restrict__ dinv, const float* __restrict__ bias,
    float* __restrict__ out, int n) {
    int v = blockIdx.x * 4 + (threadIdx.x >> 6);
    if (v >= n) return;
    int lane = threadIdx.x & 63;
    int base = rowptr[v], cnt = deg[v];
    float acc0 = 0.f, acc1 = 0.f;
    for (int j0 = 0; j0 < cnt; j0 += 64) {
        int nj = min(64, cnt - j0);
        int ul = 0; float wl = 0.f;
        if (lane < nj) { ul = csr[base + j0 + lane]; wl = dinv[ul]; }
        for (int j = 0; j < nj; j++) {
            int u = __shfl(ul, j);
            float w = __shfl(wl, j);
            const float* hp = H + (size_t)u * 128;
            acc0 += w * hp[lane];
            acc1 += w * hp[lane + 64];
        }
    }
    float dv = dinv[v];
    const float* hv = H + (size_t)v * 128;
    float sl = 2.f * dv * dv;
    float v0 = dv * acc0 + sl * hv[lane] + bias[lane];
    float v1 = dv * acc1 + sl * hv[lane + 64] + bias[lane + 64];
    float* op = out + (size_t)v * 128;
    op[lane] = fmaxf(v0, 0.f);
    op[lane + 64] = fmaxf(v1, 0.f);
}

__global__ __launch_bounds__(256) void agg_lsm_64(
    const float* __restrict__ H, const int* __restrict__ csr,
    const int* __restrict__ rowptr, const int* __restrict__ deg,
    const float* __restrict__ dinv, const float* __restrict__ bias,
    float* __restrict__ out, int n) {
    int v = blockIdx.x * 4 + (threadIdx.x >> 6);
    if (v >= n) return;
    int lane = threadIdx.x & 63;
    int base = rowptr[v], cnt = deg[v];
    float acc = 0.f;
    for (int j0 = 0; j0 < cnt; j0 += 64) {
        int nj = min(64, cnt - j0);
        int ul = 0; float wl = 0.f;
        if (lane < nj) { ul = csr[base + j0 + lane]; wl = dinv[ul]; }
        for (int j = 0; j < nj; j++) {
            int u = __shfl(ul, j);
            float w = __shfl(wl, j);
            acc += w * H[(size_t)u * 64 + lane];
        }
    }
    float dv = dinv[v];
    float val = dv * acc + 2.f * dv * dv * H[(size_t)v * 64 + lane] + bias[lane];
    // log_softmax across the 64 lanes (one channel per lane)
    float m = val;
    for (int o = 32; o > 0; o >>= 1) m = fmaxf(m, __shfl_xor(m, o));
    float e = __expf(val - m);
    float ssum = e;
    for (int o = 32; o > 0; o >>= 1) ssum += __shfl_xor(ssum, o);
    out[(size_t)v * 64 + lane] = val - m - __logf(ssum);
}

// ---------------- launch ----------------

extern "C" void kernel_launch(void* const* d_in, const int* in_sizes, int n_in,
                              void* d_out, int out_size, void* d_ws, size_t ws_size,
                              hipStream_t stream) {
    const float* x  = (const float*)d_in[0];
    const int*   ei = (const int*)d_in[1];
    const float* W1 = (const float*)d_in[2];
    const float* b1 = (const float*)d_in[3];
    const float* W2 = (const float*)d_in[4];
    const float* b2 = (const float*)d_in[5];
    float* out = (float*)d_out;

    const int N = in_sizes[0] / IN_CH;  // 100000
    const int E = in_sizes[1] / 2;      // 1600000
    const int* src = ei;
    const int* dst = ei + E;

    char* w = (char*)d_ws;
    size_t off = 0;
    auto alloc = [&](size_t bytes) -> char* {
        char* p = w + off;
        off = (off + bytes + 255) & ~(size_t)255;
        return p;
    };
    int*   deg    = (int*)alloc((size_t)N * 4);
    int*   rowptr = (int*)alloc((size_t)N * 4);
    int*   cursor = (int*)alloc((size_t)N * 4);
    int*   bsum   = (int*)alloc(512 * 4);
    int*   boff   = (int*)alloc(512 * 4);
    float* dinv   = (float*)alloc((size_t)N * 4);
    int*   csr    = (int*)alloc((size_t)E * 4);
    float* H1     = (float*)alloc((size_t)N * HID_CH * 4);
    float* A1     = (float*)alloc((size_t)N * HID_CH * 4);
    float* H2     = H1;  // H1 dead after agg1; reuse for layer-2 GEMM output

    hipMemsetAsync(deg, 0, (size_t)N * 4, stream);

    int gE = (E + 255) / 256;
    int gN = (N + 255) / 256;

    count_deg<<<gE, 256, 0, stream>>>(dst, deg, E);
    scan1<<<gN, 256, 0, stream>>>(deg, rowptr, bsum, N);
    scan2<<<1, 512, 0, stream>>>(bsum, boff, gN);
    scan3<<<gN, 256, 0, stream>>>(rowptr, boff, cursor, N);
    dinv_k<<<gN, 256, 0, stream>>>(deg, dinv, N);
    fill_csr<<<gE, 256, 0, stream>>>(src, dst, cursor, csr, E);

    gemm_k128<128, 16><<<(N + 127) / 128, 256, 0, stream>>>(x, W1, H1, N);
    agg_relu_128<<<(N + 3) / 4, 256, 0, stream>>>(H1, csr, rowptr, deg, dinv, b1, A1, N);
    gemm_k128<64, 32><<<(N + 127) / 128, 256, 0, stream>>>(A1, W2, H2, N);
    agg_lsm_64<<<(N + 3) / 4, 256, 0, stream>>>(H2, csr, rowptr, deg, dinv, b2, out, N);
}

// Round 2
// 569.394 us; speedup vs baseline: 1.1037x; 1.1037x over previous
//
#include <hip/hip_runtime.h>
#include <cstdint>
#include <cstddef>

#define IN_CH 128
#define HID_CH 128
#define OUT_CH 64
#define BSH 8        // nodes per bucket = 256
#define PB 4096      // edges per part1 block

// ---------------- CSR build ----------------

__global__ void count_deg(const int* __restrict__ dst, int* __restrict__ deg, int E) {
    int e = blockIdx.x * 256 + threadIdx.x;
    if (e < E) atomicAdd(&deg[dst[e]], 1);
}

__global__ void scan1(const int* __restrict__ deg, int* __restrict__ rowptr,
                      int* __restrict__ bsum, int n) {
    __shared__ int s[256];
    int t = threadIdx.x;
    int i = blockIdx.x * 256 + t;
    int v = (i < n) ? deg[i] : 0;
    s[t] = v;
    __syncthreads();
    for (int o = 1; o < 256; o <<= 1) {
        int add = (t >= o) ? s[t - o] : 0;
        __syncthreads();
        s[t] += add;
        __syncthreads();
    }
    if (i < n) rowptr[i] = s[t] - v;        // exclusive within block
    if (t == 255) bsum[blockIdx.x] = s[255];
}

__global__ void scan2(const int* __restrict__ bsum, int* __restrict__ boff, int nb) {
    __shared__ int s[512];
    int t = threadIdx.x;
    int v = (t < nb) ? bsum[t] : 0;
    s[t] = v;
    __syncthreads();
    for (int o = 1; o < 512; o <<= 1) {
        int add = (t >= o) ? s[t - o] : 0;
        __syncthreads();
        s[t] += add;
        __syncthreads();
    }
    if (t < nb) boff[t] = s[t] - v;         // exclusive block offsets
}

__global__ void scan3(int* __restrict__ rowptr, const int* __restrict__ boff,
                      int* __restrict__ cursor, int n) {
    int i = blockIdx.x * 256 + threadIdx.x;
    if (i < n) {
        int v = rowptr[i] + boff[blockIdx.x];
        rowptr[i] = v;
        cursor[i] = v;
    }
}

__global__ void dinv_k(const int* __restrict__ deg, float* __restrict__ dinv, int n) {
    int i = blockIdx.x * 256 + threadIdx.x;
    if (i < n) dinv[i] = rsqrtf((float)(deg[i] + 2));  // +2 self-loops
}

// part1: block-local histogram partition of edges into 256-node buckets.
// Each block reserves a contiguous run per bucket -> dense single-CU writes.
__global__ __launch_bounds__(256) void part1(
    const int* __restrict__ src, const int* __restrict__ dst,
    const int* __restrict__ rowptr, int* __restrict__ bcur,
    int2* __restrict__ pairBuf, int E, int NB) {
    __shared__ int hist[512];
    __shared__ int base[512];
    int t = threadIdx.x;
    int e0 = blockIdx.x * PB;
    int cnt = min(PB, E - e0);
    for (int b = t; b < NB; b += 256) hist[b] = 0;
    __syncthreads();
    for (int i = t; i < cnt; i += 256)
        atomicAdd(&hist[dst[e0 + i] >> BSH], 1);
    __syncthreads();
    for (int b = t; b < NB; b += 256) {
        int h = hist[b];
        int gb = (h > 0) ? atomicAdd(&bcur[b], h) : 0;
        base[b] = rowptr[b << BSH] + gb;   // this block's run start in bucket b
        hist[b] = 0;                        // reuse as local cursor
    }
    __syncthreads();
    for (int i = t; i < cnt; i += 256) {
        int s = src[e0 + i], d = dst[e0 + i];   // L1/L2-warm re-read
        int b = d >> BSH;
        int p = base[b] + atomicAdd(&hist[b], 1);
        pairBuf[p] = make_int2(s, d);
    }
}

// part2: one block per bucket; final scatter lands in a ~16KB window.
__global__ __launch_bounds__(256) void part2(
    const int2* __restrict__ pairBuf, const int* __restrict__ rowptr,
    int* __restrict__ cursor, int* __restrict__ csr, int E, int N) {
    int b = blockIdx.x;
    int start = rowptr[b << BSH];
    int hi = (b + 1) << BSH;
    int end = (hi < N) ? rowptr[hi] : E;
    for (int i = start + threadIdx.x; i < end; i += 256) {
        int2 p = pairBuf[i];
        int q = atomicAdd(&cursor[p.y], 1);
        csr[q] = p.x;
    }
}

// ---------------- GEMM (K = 128 fixed) ----------------

template <int OUT, int RG>
__global__ __launch_bounds__(256) void gemm_k128(const float* __restrict__ A,
                                                 const float* __restrict__ W,
                                                 float* __restrict__ C, int n) {
    constexpr int K = 128, KT = 32, ROWS = 128;
    constexpr int CG = 256 / RG;   // col groups
    constexpr int TC = OUT / CG;   // cols per thread (= 8)
    constexpr int TR = ROWS / RG;  // rows per thread (8 or 4)
    static_assert(TC == 8, "layout assumes 8 cols/thread");

    __shared__ float As[ROWS][KT + 4];
    __shared__ float Ws[KT][OUT];

    const int t = threadIdx.x;
    const int row0 = blockIdx.x * ROWS;
    const int cg = t % CG, rg = t / CG;
    const int c0 = cg * TC;

    float acc[TR][TC];
    for (int i = 0; i < TR; i++)
        for (int j = 0; j < TC; j++) acc[i][j] = 0.f;

    for (int kt = 0; kt < K; kt += KT) {
        for (int i = t; i < ROWS * KT / 4; i += 256) {
            int r = i / (KT / 4), kc = i % (KT / 4);
            float4 vv = make_float4(0.f, 0.f, 0.f, 0.f);
            if (row0 + r < n)
                vv = *(const float4*)(A + (size_t)(row0 + r) * K + kt + kc * 4);
            *(float4*)&As[r][kc * 4] = vv;
        }
        for (int i = t; i < KT * OUT / 4; i += 256)
            ((float4*)&Ws[0][0])[i] = ((const float4*)(W + (size_t)kt * OUT))[i];
        __syncthreads();

        for (int k = 0; k < KT; k += 4) {
            float4 a[TR];
#pragma unroll
            for (int i = 0; i < TR; i++) a[i] = *(const float4*)&As[rg + i * RG][k];
#pragma unroll
            for (int kk = 0; kk < 4; kk++) {
                float4 b0 = *(const float4*)&Ws[k + kk][c0];
                float4 b1 = *(const float4*)&Ws[k + kk][c0 + 4];
#pragma unroll
                for (int i = 0; i < TR; i++) {
                    float av = (&a[i].x)[kk];
                    acc[i][0] += av * b0.x; acc[i][1] += av * b0.y;
                    acc[i][2] += av * b0.z; acc[i][3] += av * b0.w;
                    acc[i][4] += av * b1.x; acc[i][5] += av * b1.y;
                    acc[i][6] += av * b1.z; acc[i][7] += av * b1.w;
                }
            }
        }
        __syncthreads();
    }

    for (int i = 0; i < TR; i++) {
        int r = row0 + rg + i * RG;
        if (r < n) {
            float* cp = C + (size_t)r * OUT + c0;
            *(float4*)cp = make_float4(acc[i][0], acc[i][1], acc[i][2], acc[i][3]);
            *(float4*)(cp + 4) = make_float4(acc[i][4], acc[i][5], acc[i][6], acc[i][7]);
        }
    }
}

// ---------------- Aggregation (one wave per node) ----------------
// out[v] = dinv[v] * sum_{u in N(v)} dinv[u]*H[u] + 2*dinv[v]^2*H[v] + bias

__global__ __launch_bounds__(256) void agg_relu_128(
    const float* __restrict__ H, const int* __restrict__ csr,
    const int* __restrict__ rowptr, const int* __restrict__ deg,
    const float* __restrict__ dinv, const float* __restrict__ bias,
    float* __restrict__ out, int n) {
    int v = blockIdx.x * 4 + (threadIdx.x >> 6);
    if (v >= n) return;
    int lane = threadIdx.x & 63;
    int base = rowptr[v], cnt = deg[v];
    float2 acc = make_float2(0.f, 0.f);
    for (int j0 = 0; j0 < cnt; j0 += 64) {
        int nj = min(64, cnt - j0);
        int ul = 0; float wl = 0.f;
        if (lane < nj) { ul = csr[base + j0 + lane]; wl = dinv[ul]; }
        for (int j = 0; j < nj; j++) {
            int u = __shfl(ul, j);
            float w = __shfl(wl, j);
            float2 hv = ((const float2*)(H + (size_t)u * 128))[lane];
            acc.x += w * hv.x;
            acc.y += w * hv.y;
        }
    }
    float dv = dinv[v];
    float sl = 2.f * dv * dv;
    float2 hv = ((const float2*)(H + (size_t)v * 128))[lane];
    float2 bb = ((const float2*)bias)[lane];
    float o0 = dv * acc.x + sl * hv.x + bb.x;
    float o1 = dv * acc.y + sl * hv.y + bb.y;
    ((float2*)(out + (size_t)v * 128))[lane] =
        make_float2(fmaxf(o0, 0.f), fmaxf(o1, 0.f));
}

__global__ __launch_bounds__(256) void agg_lsm_64(
    const float* __restrict__ H, const int* __restrict__ csr,
    const int* __restrict__ rowptr, const int* __restrict__ deg,
    const float* __restrict__ dinv, const float* __restrict__ bias,
    float* __restrict__ out, int n) {
    int v = blockIdx.x * 4 + (threadIdx.x >> 6);
    if (v >= n) return;
    int lane = threadIdx.x & 63;
    int base = rowptr[v], cnt = deg[v];
    float acc = 0.f;
    for (int j0 = 0; j0 < cnt; j0 += 64) {
        int nj = min(64, cnt - j0);
        int ul = 0; float wl = 0.f;
        if (lane < nj) { ul = csr[base + j0 + lane]; wl = dinv[ul]; }
        for (int j = 0; j < nj; j++) {
            int u = __shfl(ul, j);
            float w = __shfl(wl, j);
            acc += w * H[(size_t)u * 64 + lane];
        }
    }
    float dv = dinv[v];
    float val = dv * acc + 2.f * dv * dv * H[(size_t)v * 64 + lane] + bias[lane];
    float m = val;
    for (int o = 32; o > 0; o >>= 1) m = fmaxf(m, __shfl_xor(m, o));
    float e = __expf(val - m);
    float ssum = e;
    for (int o = 32; o > 0; o >>= 1) ssum += __shfl_xor(ssum, o);
    out[(size_t)v * 64 + lane] = val - m - __logf(ssum);
}

// ---------------- launch ----------------

extern "C" void kernel_launch(void* const* d_in, const int* in_sizes, int n_in,
                              void* d_out, int out_size, void* d_ws, size_t ws_size,
                              hipStream_t stream) {
    const float* x  = (const float*)d_in[0];
    const int*   ei = (const int*)d_in[1];
    const float* W1 = (const float*)d_in[2];
    const float* b1 = (const float*)d_in[3];
    const float* W2 = (const float*)d_in[4];
    const float* b2 = (const float*)d_in[5];
    float* out = (float*)d_out;

    const int N = in_sizes[0] / IN_CH;  // 100000
    const int E = in_sizes[1] / 2;      // 1600000
    const int* src = ei;
    const int* dst = ei + E;
    const int NB = (N + 255) >> BSH;    // 391 buckets

    char* w = (char*)d_ws;
    size_t off = 0;
    auto alloc = [&](size_t bytes) -> char* {
        char* p = w + off;
        off = (off + bytes + 255) & ~(size_t)255;
        return p;
    };
    int*   deg    = (int*)alloc((size_t)N * 4);
    int*   rowptr = (int*)alloc((size_t)N * 4);
    int*   cursor = (int*)alloc((size_t)N * 4);
    int*   bsum   = (int*)alloc(512 * 4);
    int*   boff   = (int*)alloc(512 * 4);
    int*   bcur   = (int*)alloc(512 * 4);
    float* dinv   = (float*)alloc((size_t)N * 4);
    int*   csr    = (int*)alloc((size_t)E * 4);
    float* H1     = (float*)alloc((size_t)N * HID_CH * 4);
    float* A1     = (float*)alloc((size_t)N * HID_CH * 4);
    float* H2     = H1;                  // H1 dead after agg1
    int2*  pairBuf = (int2*)A1;          // A1 not written until agg1 (after part2)

    hipMemsetAsync(deg, 0, (size_t)N * 4, stream);
    hipMemsetAsync(bcur, 0, 512 * 4, stream);

    int gE = (E + 255) / 256;
    int gN = (N + 255) / 256;

    count_deg<<<gE, 256, 0, stream>>>(dst, deg, E);
    scan1<<<gN, 256, 0, stream>>>(deg, rowptr, bsum, N);
    scan2<<<1, 512, 0, stream>>>(bsum, boff, gN);
    scan3<<<gN, 256, 0, stream>>>(rowptr, boff, cursor, N);
    dinv_k<<<gN, 256, 0, stream>>>(deg, dinv, N);
    part1<<<(E + PB - 1) / PB, 256, 0, stream>>>(src, dst, rowptr, bcur, pairBuf, E, NB);
    part2<<<NB, 256, 0, stream>>>(pairBuf, rowptr, cursor, csr, E, N);

    gemm_k128<128, 16><<<(N + 127) / 128, 256, 0, stream>>>(x, W1, H1, N);
    agg_relu_128<<<(N + 3) / 4, 256, 0, stream>>>(H1, csr, rowptr, deg, dinv, b1, A1, N);
    gemm_k128<64, 32><<<(N + 127) / 128, 256, 0, stream>>>(A1, W2, H2, N);
    agg_lsm_64<<<(N + 3) / 4, 256, 0, stream>>>(H2, csr, rowptr, deg, dinv, b2, out, N);
}

// Round 3
// 520.810 us; speedup vs baseline: 1.2067x; 1.0933x over previous
//
#include <hip/hip_runtime.h>
#include <cstdint>
#include <cstddef>

#define IN_CH 128
#define HID_CH 128
#define OUT_CH 64
#define BSH 8        // nodes per bucket = 256
#define PB 4096      // edges per part1 block

// ---------------- CSR build ----------------

__global__ void count_deg(const int* __restrict__ dst, int* __restrict__ deg, int E) {
    int e = blockIdx.x * 256 + threadIdx.x;
    if (e < E) atomicAdd(&deg[dst[e]], 1);
}

__global__ void scan1(const int* __restrict__ deg, int* __restrict__ rowptr,
                      int* __restrict__ bsum, int n) {
    __shared__ int s[256];
    int t = threadIdx.x;
    int i = blockIdx.x * 256 + t;
    int v = (i < n) ? deg[i] : 0;
    s[t] = v;
    __syncthreads();
    for (int o = 1; o < 256; o <<= 1) {
        int add = (t >= o) ? s[t - o] : 0;
        __syncthreads();
        s[t] += add;
        __syncthreads();
    }
    if (i < n) rowptr[i] = s[t] - v;        // exclusive within block
    if (t == 255) bsum[blockIdx.x] = s[255];
}

__global__ void scan2(const int* __restrict__ bsum, int* __restrict__ boff, int nb) {
    __shared__ int s[512];
    int t = threadIdx.x;
    int v = (t < nb) ? bsum[t] : 0;
    s[t] = v;
    __syncthreads();
    for (int o = 1; o < 512; o <<= 1) {
        int add = (t >= o) ? s[t - o] : 0;
        __syncthreads();
        s[t] += add;
        __syncthreads();
    }
    if (t < nb) boff[t] = s[t] - v;         // exclusive block offsets
}

__global__ void scan3(int* __restrict__ rowptr, const int* __restrict__ boff,
                      int* __restrict__ cursor, int n) {
    int i = blockIdx.x * 256 + threadIdx.x;
    if (i < n) {
        int v = rowptr[i] + boff[blockIdx.x];
        rowptr[i] = v;
        cursor[i] = v;
    }
}

__global__ void dinv_k(const int* __restrict__ deg, float* __restrict__ dinv, int n) {
    int i = blockIdx.x * 256 + threadIdx.x;
    if (i < n) dinv[i] = rsqrtf((float)(deg[i] + 2));  // +2 self-loops
}

// part1: block-local histogram partition of edges into 256-node buckets.
__global__ __launch_bounds__(256) void part1(
    const int* __restrict__ src, const int* __restrict__ dst,
    const int* __restrict__ rowptr, int* __restrict__ bcur,
    int2* __restrict__ pairBuf, int E, int NB) {
    __shared__ int hist[512];
    __shared__ int base[512];
    int t = threadIdx.x;
    int e0 = blockIdx.x * PB;
    int cnt = min(PB, E - e0);
    for (int b = t; b < NB; b += 256) hist[b] = 0;
    __syncthreads();
    for (int i = t; i < cnt; i += 256)
        atomicAdd(&hist[dst[e0 + i] >> BSH], 1);
    __syncthreads();
    for (int b = t; b < NB; b += 256) {
        int h = hist[b];
        int gb = (h > 0) ? atomicAdd(&bcur[b], h) : 0;
        base[b] = rowptr[b << BSH] + gb;
        hist[b] = 0;
    }
    __syncthreads();
    for (int i = t; i < cnt; i += 256) {
        int s = src[e0 + i], d = dst[e0 + i];
        int b = d >> BSH;
        int p = base[b] + atomicAdd(&hist[b], 1);
        pairBuf[p] = make_int2(s, d);
    }
}

// part2: one block per bucket; final scatter lands in a ~16KB window.
__global__ __launch_bounds__(256) void part2(
    const int2* __restrict__ pairBuf, const int* __restrict__ rowptr,
    int* __restrict__ cursor, int* __restrict__ csr, int E, int N) {
    int b = blockIdx.x;
    int start = rowptr[b << BSH];
    int hi = (b + 1) << BSH;
    int end = (hi < N) ? rowptr[hi] : E;
    for (int i = start + threadIdx.x; i < end; i += 256) {
        int2 p = pairBuf[i];
        int q = atomicAdd(&cursor[p.y], 1);
        csr[q] = p.x;
    }
}

// ---------------- GEMM (K = 128 fixed) ----------------

template <int OUT, int RG>
__global__ __launch_bounds__(256) void gemm_k128(const float* __restrict__ A,
                                                 const float* __restrict__ W,
                                                 float* __restrict__ C, int n) {
    constexpr int K = 128, KT = 32, ROWS = 128;
    constexpr int CG = 256 / RG;
    constexpr int TC = OUT / CG;
    constexpr int TR = ROWS / RG;
    static_assert(TC == 8, "layout assumes 8 cols/thread");

    __shared__ float As[ROWS][KT + 4];
    __shared__ float Ws[KT][OUT];

    const int t = threadIdx.x;
    const int row0 = blockIdx.x * ROWS;
    const int cg = t % CG, rg = t / CG;
    const int c0 = cg * TC;

    float acc[TR][TC];
    for (int i = 0; i < TR; i++)
        for (int j = 0; j < TC; j++) acc[i][j] = 0.f;

    for (int kt = 0; kt < K; kt += KT) {
        for (int i = t; i < ROWS * KT / 4; i += 256) {
            int r = i / (KT / 4), kc = i % (KT / 4);
            float4 vv = make_float4(0.f, 0.f, 0.f, 0.f);
            if (row0 + r < n)
                vv = *(const float4*)(A + (size_t)(row0 + r) * K + kt + kc * 4);
            *(float4*)&As[r][kc * 4] = vv;
        }
        for (int i = t; i < KT * OUT / 4; i += 256)
            ((float4*)&Ws[0][0])[i] = ((const float4*)(W + (size_t)kt * OUT))[i];
        __syncthreads();

        for (int k = 0; k < KT; k += 4) {
            float4 a[TR];
#pragma unroll
            for (int i = 0; i < TR; i++) a[i] = *(const float4*)&As[rg + i * RG][k];
#pragma unroll
            for (int kk = 0; kk < 4; kk++) {
                float4 b0 = *(const float4*)&Ws[k + kk][c0];
                float4 b1 = *(const float4*)&Ws[k + kk][c0 + 4];
#pragma unroll
                for (int i = 0; i < TR; i++) {
                    float av = (&a[i].x)[kk];
                    acc[i][0] += av * b0.x; acc[i][1] += av * b0.y;
                    acc[i][2] += av * b0.z; acc[i][3] += av * b0.w;
                    acc[i][4] += av * b1.x; acc[i][5] += av * b1.y;
                    acc[i][6] += av * b1.z; acc[i][7] += av * b1.w;
                }
            }
        }
        __syncthreads();
    }

    for (int i = 0; i < TR; i++) {
        int r = row0 + rg + i * RG;
        if (r < n) {
            float* cp = C + (size_t)r * OUT + c0;
            *(float4*)cp = make_float4(acc[i][0], acc[i][1], acc[i][2], acc[i][3]);
            *(float4*)(cp + 4) = make_float4(acc[i][4], acc[i][5], acc[i][6], acc[i][7]);
        }
    }
}

// ---------------- Aggregation (one wave per node, 4-way edge ILP) ----------------
// out[v] = dinv[v] * sum_{u in N(v)} dinv[u]*H[u] + 2*dinv[v]^2*H[v] + bias

__global__ __launch_bounds__(256) void agg_relu_128(
    const float* __restrict__ H, const int* __restrict__ csr,
    const int* __restrict__ rowptr, const int* __restrict__ deg,
    const float* __restrict__ dinv, const float* __restrict__ bias,
    float* __restrict__ out, int n) {
    int v = blockIdx.x * 4 + (threadIdx.x >> 6);
    if (v >= n) return;
    int lane = threadIdx.x & 63;
    int base = rowptr[v], cnt = deg[v];
    float2 a0 = make_float2(0.f, 0.f), a1 = a0, a2 = a0, a3 = a0;
    for (int j0 = 0; j0 < cnt; j0 += 64) {
        int nj = min(64, cnt - j0);
        int ul = 0; float wl = 0.f;
        if (lane < nj) { ul = csr[base + j0 + lane]; wl = dinv[ul]; }
        int j = 0;
        for (; j + 4 <= nj; j += 4) {
            int u0 = __shfl(ul, j),     u1 = __shfl(ul, j + 1);
            int u2 = __shfl(ul, j + 2), u3 = __shfl(ul, j + 3);
            float w0 = __shfl(wl, j),     w1 = __shfl(wl, j + 1);
            float w2 = __shfl(wl, j + 2), w3 = __shfl(wl, j + 3);
            float2 h0 = ((const float2*)(H + (size_t)u0 * 128))[lane];
            float2 h1 = ((const float2*)(H + (size_t)u1 * 128))[lane];
            float2 h2 = ((const float2*)(H + (size_t)u2 * 128))[lane];
            float2 h3 = ((const float2*)(H + (size_t)u3 * 128))[lane];
            a0.x += w0 * h0.x; a0.y += w0 * h0.y;
            a1.x += w1 * h1.x; a1.y += w1 * h1.y;
            a2.x += w2 * h2.x; a2.y += w2 * h2.y;
            a3.x += w3 * h3.x; a3.y += w3 * h3.y;
        }
        for (; j < nj; j++) {
            int u = __shfl(ul, j);
            float w = __shfl(wl, j);
            float2 hv = ((const float2*)(H + (size_t)u * 128))[lane];
            a0.x += w * hv.x; a0.y += w * hv.y;
        }
    }
    float2 acc = make_float2((a0.x + a1.x) + (a2.x + a3.x),
                             (a0.y + a1.y) + (a2.y + a3.y));
    float dv = dinv[v];
    float sl = 2.f * dv * dv;
    float2 hv = ((const float2*)(H + (size_t)v * 128))[lane];
    float2 bb = ((const float2*)bias)[lane];
    float o0 = dv * acc.x + sl * hv.x + bb.x;
    float o1 = dv * acc.y + sl * hv.y + bb.y;
    ((float2*)(out + (size_t)v * 128))[lane] =
        make_float2(fmaxf(o0, 0.f), fmaxf(o1, 0.f));
}

__global__ __launch_bounds__(256) void agg_lsm_64(
    const float* __restrict__ H, const int* __restrict__ csr,
    const int* __restrict__ rowptr, const int* __restrict__ deg,
    const float* __restrict__ dinv, const float* __restrict__ bias,
    float* __restrict__ out, int n) {
    int v = blockIdx.x * 4 + (threadIdx.x >> 6);
    if (v >= n) return;
    int lane = threadIdx.x & 63;
    int base = rowptr[v], cnt = deg[v];
    float a0 = 0.f, a1 = 0.f, a2 = 0.f, a3 = 0.f;
    for (int j0 = 0; j0 < cnt; j0 += 64) {
        int nj = min(64, cnt - j0);
        int ul = 0; float wl = 0.f;
        if (lane < nj) { ul = csr[base + j0 + lane]; wl = dinv[ul]; }
        int j = 0;
        for (; j + 4 <= nj; j += 4) {
            int u0 = __shfl(ul, j),     u1 = __shfl(ul, j + 1);
            int u2 = __shfl(ul, j + 2), u3 = __shfl(ul, j + 3);
            float w0 = __shfl(wl, j),     w1 = __shfl(wl, j + 1);
            float w2 = __shfl(wl, j + 2), w3 = __shfl(wl, j + 3);
            float h0 = H[(size_t)u0 * 64 + lane];
            float h1 = H[(size_t)u1 * 64 + lane];
            float h2 = H[(size_t)u2 * 64 + lane];
            float h3 = H[(size_t)u3 * 64 + lane];
            a0 += w0 * h0; a1 += w1 * h1; a2 += w2 * h2; a3 += w3 * h3;
        }
        for (; j < nj; j++) {
            int u = __shfl(ul, j);
            float w = __shfl(wl, j);
            a0 += w * H[(size_t)u * 64 + lane];
        }
    }
    float acc = (a0 + a1) + (a2 + a3);
    float dv = dinv[v];
    float val = dv * acc + 2.f * dv * dv * H[(size_t)v * 64 + lane] + bias[lane];
    float m = val;
    for (int o = 32; o > 0; o >>= 1) m = fmaxf(m, __shfl_xor(m, o));
    float e = __expf(val - m);
    float ssum = e;
    for (int o = 32; o > 0; o >>= 1) ssum += __shfl_xor(ssum, o);
    out[(size_t)v * 64 + lane] = val - m - __logf(ssum);
}

// ---------------- launch ----------------

extern "C" void kernel_launch(void* const* d_in, const int* in_sizes, int n_in,
                              void* d_out, int out_size, void* d_ws, size_t ws_size,
                              hipStream_t stream) {
    const float* x  = (const float*)d_in[0];
    const int*   ei = (const int*)d_in[1];
    const float* W1 = (const float*)d_in[2];
    const float* b1 = (const float*)d_in[3];
    const float* W2 = (const float*)d_in[4];
    const float* b2 = (const float*)d_in[5];
    float* out = (float*)d_out;

    const int N = in_sizes[0] / IN_CH;  // 100000
    const int E = in_sizes[1] / 2;      // 1600000
    const int* src = ei;
    const int* dst = ei + E;
    const int NB = (N + 255) >> BSH;    // 391 buckets

    char* w = (char*)d_ws;
    size_t off = 0;
    auto alloc = [&](size_t bytes) -> char* {
        char* p = w + off;
        off = (off + bytes + 255) & ~(size_t)255;
        return p;
    };
    int*   deg    = (int*)alloc((size_t)N * 4);
    int*   rowptr = (int*)alloc((size_t)N * 4);
    int*   cursor = (int*)alloc((size_t)N * 4);
    int*   bsum   = (int*)alloc(512 * 4);
    int*   boff   = (int*)alloc(512 * 4);
    int*   bcur   = (int*)alloc(512 * 4);
    float* dinv   = (float*)alloc((size_t)N * 4);
    int*   csr    = (int*)alloc((size_t)E * 4);
    float* H1     = (float*)alloc((size_t)N * HID_CH * 4);
    float* A1     = (float*)alloc((size_t)N * HID_CH * 4);
    float* H2     = H1;                  // H1 dead after agg1
    int2*  pairBuf = (int2*)A1;          // A1 not written until agg1 (after part2)

    hipMemsetAsync(deg, 0, (size_t)N * 4, stream);
    hipMemsetAsync(bcur, 0, 512 * 4, stream);

    int gE = (E + 255) / 256;
    int gN = (N + 255) / 256;

    count_deg<<<gE, 256, 0, stream>>>(dst, deg, E);
    scan1<<<gN, 256, 0, stream>>>(deg, rowptr, bsum, N);
    scan2<<<1, 512, 0, stream>>>(bsum, boff, gN);
    scan3<<<gN, 256, 0, stream>>>(rowptr, boff, cursor, N);
    dinv_k<<<gN, 256, 0, stream>>>(deg, dinv, N);
    part1<<<(E + PB - 1) / PB, 256, 0, stream>>>(src, dst, rowptr, bcur, pairBuf, E, NB);
    part2<<<NB, 256, 0, stream>>>(pairBuf, rowptr, cursor, csr, E, N);

    gemm_k128<128, 16><<<(N + 127) / 128, 256, 0, stream>>>(x, W1, H1, N);
    agg_relu_128<<<(N + 3) / 4, 256, 0, stream>>>(H1, csr, rowptr, deg, dinv, b1, A1, N);
    gemm_k128<64, 32><<<(N + 127) / 128, 256, 0, stream>>>(A1, W2, H2, N);
    agg_lsm_64<<<(N + 3) / 4, 256, 0, stream>>>(H2, csr, rowptr, deg, dinv, b2, out, N);
}

// Round 4
// 465.096 us; speedup vs baseline: 1.3512x; 1.1198x over previous
//
#include <hip/hip_runtime.h>
#include <cstdint>
#include <cstddef>

#define IN_CH 128
#define HID_CH 128
#define OUT_CH 64
#define BSH 8        // nodes per bucket = 256
#define PB 4096      // edges per part1 block

typedef unsigned int uint32;
typedef unsigned short ushort16_t;

// float -> bf16 with round-to-nearest-even (values are finite; NaN path not needed)
static __device__ __forceinline__ unsigned short f2bf(float f) {
    uint32 u = __float_as_uint(f);
    u += 0x7fffu + ((u >> 16) & 1u);
    return (unsigned short)(u >> 16);
}
static __device__ __forceinline__ float bflo(uint32 packed) {  // element at lower addr
    return __uint_as_float(packed << 16);
}
static __device__ __forceinline__ float bfhi(uint32 packed) {
    return __uint_as_float(packed & 0xffff0000u);
}

// ---------------- CSR build ----------------

__global__ void count_deg(const int* __restrict__ dst, int* __restrict__ deg, int E) {
    int e = blockIdx.x * 256 + threadIdx.x;
    if (e < E) atomicAdd(&deg[dst[e]], 1);
}

__global__ void scan1(const int* __restrict__ deg, int* __restrict__ rowptr,
                      int* __restrict__ bsum, int n) {
    __shared__ int s[256];
    int t = threadIdx.x;
    int i = blockIdx.x * 256 + t;
    int v = (i < n) ? deg[i] : 0;
    s[t] = v;
    __syncthreads();
    for (int o = 1; o < 256; o <<= 1) {
        int add = (t >= o) ? s[t - o] : 0;
        __syncthreads();
        s[t] += add;
        __syncthreads();
    }
    if (i < n) rowptr[i] = s[t] - v;
    if (t == 255) bsum[blockIdx.x] = s[255];
}

__global__ void scan2(const int* __restrict__ bsum, int* __restrict__ boff, int nb) {
    __shared__ int s[512];
    int t = threadIdx.x;
    int v = (t < nb) ? bsum[t] : 0;
    s[t] = v;
    __syncthreads();
    for (int o = 1; o < 512; o <<= 1) {
        int add = (t >= o) ? s[t - o] : 0;
        __syncthreads();
        s[t] += add;
        __syncthreads();
    }
    if (t < nb) boff[t] = s[t] - v;
}

__global__ void scan3(int* __restrict__ rowptr, const int* __restrict__ boff,
                      int* __restrict__ cursor, int n) {
    int i = blockIdx.x * 256 + threadIdx.x;
    if (i < n) {
        int v = rowptr[i] + boff[blockIdx.x];
        rowptr[i] = v;
        cursor[i] = v;
    }
}

__global__ void dinv_k(const int* __restrict__ deg, float* __restrict__ dinv, int n) {
    int i = blockIdx.x * 256 + threadIdx.x;
    if (i < n) dinv[i] = rsqrtf((float)(deg[i] + 2));  // +2 self-loops
}

__global__ __launch_bounds__(256) void part1(
    const int* __restrict__ src, const int* __restrict__ dst,
    const int* __restrict__ rowptr, int* __restrict__ bcur,
    int2* __restrict__ pairBuf, int E, int NB) {
    __shared__ int hist[512];
    __shared__ int base[512];
    int t = threadIdx.x;
    int e0 = blockIdx.x * PB;
    int cnt = min(PB, E - e0);
    for (int b = t; b < NB; b += 256) hist[b] = 0;
    __syncthreads();
    for (int i = t; i < cnt; i += 256)
        atomicAdd(&hist[dst[e0 + i] >> BSH], 1);
    __syncthreads();
    for (int b = t; b < NB; b += 256) {
        int h = hist[b];
        int gb = (h > 0) ? atomicAdd(&bcur[b], h) : 0;
        base[b] = rowptr[b << BSH] + gb;
        hist[b] = 0;
    }
    __syncthreads();
    for (int i = t; i < cnt; i += 256) {
        int s = src[e0 + i], d = dst[e0 + i];
        int b = d >> BSH;
        int p = base[b] + atomicAdd(&hist[b], 1);
        pairBuf[p] = make_int2(s, d);
    }
}

__global__ __launch_bounds__(256) void part2(
    const int2* __restrict__ pairBuf, const int* __restrict__ rowptr,
    int* __restrict__ cursor, int* __restrict__ csr, int E, int N) {
    int b = blockIdx.x;
    int start = rowptr[b << BSH];
    int hi = (b + 1) << BSH;
    int end = (hi < N) ? rowptr[hi] : E;
    for (int i = start + threadIdx.x; i < end; i += 256) {
        int2 p = pairBuf[i];
        int q = atomicAdd(&cursor[p.y], 1);
        csr[q] = p.x;
    }
}

// ---------------- GEMM (K = 128 fixed), bf16 output ----------------

template <int OUT, int RG>
__global__ __launch_bounds__(256) void gemm_k128_bf(const float* __restrict__ A,
                                                    const float* __restrict__ W,
                                                    unsigned short* __restrict__ C,
                                                    int n) {
    constexpr int K = 128, KT = 32, ROWS = 128;
    constexpr int CG = 256 / RG;
    constexpr int TC = OUT / CG;
    constexpr int TR = ROWS / RG;
    static_assert(TC == 8, "layout assumes 8 cols/thread");

    __shared__ float As[ROWS][KT + 4];
    __shared__ float Ws[KT][OUT];

    const int t = threadIdx.x;
    const int row0 = blockIdx.x * ROWS;
    const int cg = t % CG, rg = t / CG;
    const int c0 = cg * TC;

    float acc[TR][8];
    for (int i = 0; i < TR; i++)
        for (int j = 0; j < 8; j++) acc[i][j] = 0.f;

    for (int kt = 0; kt < K; kt += KT) {
        for (int i = t; i < ROWS * KT / 4; i += 256) {
            int r = i / (KT / 4), kc = i % (KT / 4);
            float4 vv = make_float4(0.f, 0.f, 0.f, 0.f);
            if (row0 + r < n)
                vv = *(const float4*)(A + (size_t)(row0 + r) * K + kt + kc * 4);
            *(float4*)&As[r][kc * 4] = vv;
        }
        for (int i = t; i < KT * OUT / 4; i += 256)
            ((float4*)&Ws[0][0])[i] = ((const float4*)(W + (size_t)kt * OUT))[i];
        __syncthreads();

        for (int k = 0; k < KT; k += 4) {
            float4 a[TR];
#pragma unroll
            for (int i = 0; i < TR; i++) a[i] = *(const float4*)&As[rg + i * RG][k];
#pragma unroll
            for (int kk = 0; kk < 4; kk++) {
                float4 b0 = *(const float4*)&Ws[k + kk][c0];
                float4 b1 = *(const float4*)&Ws[k + kk][c0 + 4];
#pragma unroll
                for (int i = 0; i < TR; i++) {
                    float av = (&a[i].x)[kk];
                    acc[i][0] += av * b0.x; acc[i][1] += av * b0.y;
                    acc[i][2] += av * b0.z; acc[i][3] += av * b0.w;
                    acc[i][4] += av * b1.x; acc[i][5] += av * b1.y;
                    acc[i][6] += av * b1.z; acc[i][7] += av * b1.w;
                }
            }
        }
        __syncthreads();
    }

    for (int i = 0; i < TR; i++) {
        int r = row0 + rg + i * RG;
        if (r < n) {
            uint4 pk;
            pk.x = (uint32)f2bf(acc[i][0]) | ((uint32)f2bf(acc[i][1]) << 16);
            pk.y = (uint32)f2bf(acc[i][2]) | ((uint32)f2bf(acc[i][3]) << 16);
            pk.z = (uint32)f2bf(acc[i][4]) | ((uint32)f2bf(acc[i][5]) << 16);
            pk.w = (uint32)f2bf(acc[i][6]) | ((uint32)f2bf(acc[i][7]) << 16);
            *(uint4*)(C + (size_t)r * OUT + c0) = pk;
        }
    }
}

// ---------------- Aggregation (one wave per node, 4-way edge ILP, bf16 gather) ----

__global__ __launch_bounds__(256) void agg_relu_128(
    const unsigned short* __restrict__ H, const int* __restrict__ csr,
    const int* __restrict__ rowptr, const int* __restrict__ deg,
    const float* __restrict__ dinv, const float* __restrict__ bias,
    float* __restrict__ out, int n) {
    int v = blockIdx.x * 4 + (threadIdx.x >> 6);
    if (v >= n) return;
    int lane = threadIdx.x & 63;
    int base = rowptr[v], cnt = deg[v];
    float2 a0 = make_float2(0.f, 0.f), a1 = a0, a2 = a0, a3 = a0;
    for (int j0 = 0; j0 < cnt; j0 += 64) {
        int nj = min(64, cnt - j0);
        int ul = 0; float wl = 0.f;
        if (lane < nj) { ul = csr[base + j0 + lane]; wl = dinv[ul]; }
        int j = 0;
        for (; j + 4 <= nj; j += 4) {
            int u0 = __shfl(ul, j),     u1 = __shfl(ul, j + 1);
            int u2 = __shfl(ul, j + 2), u3 = __shfl(ul, j + 3);
            float w0 = __shfl(wl, j),     w1 = __shfl(wl, j + 1);
            float w2 = __shfl(wl, j + 2), w3 = __shfl(wl, j + 3);
            uint32 h0 = *(const uint32*)(H + (size_t)u0 * 128 + lane * 2);
            uint32 h1 = *(const uint32*)(H + (size_t)u1 * 128 + lane * 2);
            uint32 h2 = *(const uint32*)(H + (size_t)u2 * 128 + lane * 2);
            uint32 h3 = *(const uint32*)(H + (size_t)u3 * 128 + lane * 2);
            a0.x += w0 * bflo(h0); a0.y += w0 * bfhi(h0);
            a1.x += w1 * bflo(h1); a1.y += w1 * bfhi(h1);
            a2.x += w2 * bflo(h2); a2.y += w2 * bfhi(h2);
            a3.x += w3 * bflo(h3); a3.y += w3 * bfhi(h3);
        }
        for (; j < nj; j++) {
            int u = __shfl(ul, j);
            float w = __shfl(wl, j);
            uint32 hv = *(const uint32*)(H + (size_t)u * 128 + lane * 2);
            a0.x += w * bflo(hv); a0.y += w * bfhi(hv);
        }
    }
    float2 acc = make_float2((a0.x + a1.x) + (a2.x + a3.x),
                             (a0.y + a1.y) + (a2.y + a3.y));
    float dv = dinv[v];
    float sl = 2.f * dv * dv;
    uint32 hv = *(const uint32*)(H + (size_t)v * 128 + lane * 2);
    float2 bb = ((const float2*)bias)[lane];
    float o0 = dv * acc.x + sl * bflo(hv) + bb.x;
    float o1 = dv * acc.y + sl * bfhi(hv) + bb.y;
    ((float2*)(out + (size_t)v * 128))[lane] =
        make_float2(fmaxf(o0, 0.f), fmaxf(o1, 0.f));
}

__global__ __launch_bounds__(256) void agg_lsm_64(
    const unsigned short* __restrict__ H, const int* __restrict__ csr,
    const int* __restrict__ rowptr, const int* __restrict__ deg,
    const float* __restrict__ dinv, const float* __restrict__ bias,
    float* __restrict__ out, int n) {
    int v = blockIdx.x * 4 + (threadIdx.x >> 6);
    if (v >= n) return;
    int lane = threadIdx.x & 63;
    int base = rowptr[v], cnt = deg[v];
    float a0 = 0.f, a1 = 0.f, a2 = 0.f, a3 = 0.f;
    for (int j0 = 0; j0 < cnt; j0 += 64) {
        int nj = min(64, cnt - j0);
        int ul = 0; float wl = 0.f;
        if (lane < nj) { ul = csr[base + j0 + lane]; wl = dinv[ul]; }
        int j = 0;
        for (; j + 4 <= nj; j += 4) {
            int u0 = __shfl(ul, j),     u1 = __shfl(ul, j + 1);
            int u2 = __shfl(ul, j + 2), u3 = __shfl(ul, j + 3);
            float w0 = __shfl(wl, j),     w1 = __shfl(wl, j + 1);
            float w2 = __shfl(wl, j + 2), w3 = __shfl(wl, j + 3);
            float h0 = __uint_as_float((uint32)H[(size_t)u0 * 64 + lane] << 16);
            float h1 = __uint_as_float((uint32)H[(size_t)u1 * 64 + lane] << 16);
            float h2 = __uint_as_float((uint32)H[(size_t)u2 * 64 + lane] << 16);
            float h3 = __uint_as_float((uint32)H[(size_t)u3 * 64 + lane] << 16);
            a0 += w0 * h0; a1 += w1 * h1; a2 += w2 * h2; a3 += w3 * h3;
        }
        for (; j < nj; j++) {
            int u = __shfl(ul, j);
            float w = __shfl(wl, j);
            a0 += w * __uint_as_float((uint32)H[(size_t)u * 64 + lane] << 16);
        }
    }
    float acc = (a0 + a1) + (a2 + a3);
    float dv = dinv[v];
    float hv = __uint_as_float((uint32)H[(size_t)v * 64 + lane] << 16);
    float val = dv * acc + 2.f * dv * dv * hv + bias[lane];
    float m = val;
    for (int o = 32; o > 0; o >>= 1) m = fmaxf(m, __shfl_xor(m, o));
    float e = __expf(val - m);
    float ssum = e;
    for (int o = 32; o > 0; o >>= 1) ssum += __shfl_xor(ssum, o);
    out[(size_t)v * 64 + lane] = val - m - __logf(ssum);
}

// ---------------- launch ----------------

extern "C" void kernel_launch(void* const* d_in, const int* in_sizes, int n_in,
                              void* d_out, int out_size, void* d_ws, size_t ws_size,
                              hipStream_t stream) {
    const float* x  = (const float*)d_in[0];
    const int*   ei = (const int*)d_in[1];
    const float* W1 = (const float*)d_in[2];
    const float* b1 = (const float*)d_in[3];
    const float* W2 = (const float*)d_in[4];
    const float* b2 = (const float*)d_in[5];
    float* out = (float*)d_out;

    const int N = in_sizes[0] / IN_CH;  // 100000
    const int E = in_sizes[1] / 2;      // 1600000
    const int* src = ei;
    const int* dst = ei + E;
    const int NB = (N + 255) >> BSH;    // 391 buckets

    char* w = (char*)d_ws;
    size_t off = 0;
    auto alloc = [&](size_t bytes) -> char* {
        char* p = w + off;
        off = (off + bytes + 255) & ~(size_t)255;
        return p;
    };
    int*   deg    = (int*)alloc((size_t)N * 4);
    int*   rowptr = (int*)alloc((size_t)N * 4);
    int*   cursor = (int*)alloc((size_t)N * 4);
    int*   bsum   = (int*)alloc(512 * 4);
    int*   boff   = (int*)alloc(512 * 4);
    int*   bcur   = (int*)alloc(512 * 4);
    float* dinv   = (float*)alloc((size_t)N * 4);
    int*   csr    = (int*)alloc((size_t)E * 4);
    unsigned short* H1 = (unsigned short*)alloc((size_t)N * HID_CH * 2);  // bf16
    float* A1     = (float*)alloc((size_t)N * HID_CH * 4);                // fp32
    unsigned short* H2 = H1;             // H1 dead after agg1; bf16, smaller
    int2*  pairBuf = (int2*)A1;          // A1 not written until agg1 (after part2)

    hipMemsetAsync(deg, 0, (size_t)N * 4, stream);
    hipMemsetAsync(bcur, 0, 512 * 4, stream);

    int gE = (E + 255) / 256;
    int gN = (N + 255) / 256;

    count_deg<<<gE, 256, 0, stream>>>(dst, deg, E);
    scan1<<<gN, 256, 0, stream>>>(deg, rowptr, bsum, N);
    scan2<<<1, 512, 0, stream>>>(bsum, boff, gN);
    scan3<<<gN, 256, 0, stream>>>(rowptr, boff, cursor, N);
    dinv_k<<<gN, 256, 0, stream>>>(deg, dinv, N);
    part1<<<(E + PB - 1) / PB, 256, 0, stream>>>(src, dst, rowptr, bcur, pairBuf, E, NB);
    part2<<<NB, 256, 0, stream>>>(pairBuf, rowptr, cursor, csr, E, N);

    gemm_k128_bf<128, 16><<<(N + 127) / 128, 256, 0, stream>>>(x, W1, H1, N);
    agg_relu_128<<<(N + 3) / 4, 256, 0, stream>>>(H1, csr, rowptr, deg, dinv, b1, A1, N);
    gemm_k128_bf<64, 32><<<(N + 127) / 128, 256, 0, stream>>>(A1, W2, H2, N);
    agg_lsm_64<<<(N + 3) / 4, 256, 0, stream>>>(H2, csr, rowptr, deg, dinv, b2, out, N);
}

// Round 5
// 399.395 us; speedup vs baseline: 1.5735x; 1.1645x over previous
//
#include <hip/hip_runtime.h>
#include <cstdint>
#include <cstddef>

#define IN_CH 128
#define HID_CH 128
#define OUT_CH 64
#define BSH 8        // nodes per bucket = 256
#define PB 4096      // edges per part1 block

typedef unsigned int uint32;
typedef short bf16x8 __attribute__((ext_vector_type(8)));
typedef float f32x4 __attribute__((ext_vector_type(4)));

// float -> bf16 round-to-nearest-even
static __device__ __forceinline__ unsigned short f2bf(float f) {
    uint32 u = __float_as_uint(f);
    u += 0x7fffu + ((u >> 16) & 1u);
    return (unsigned short)(u >> 16);
}
static __device__ __forceinline__ float bflo(uint32 packed) {
    return __uint_as_float(packed << 16);
}
static __device__ __forceinline__ float bfhi(uint32 packed) {
    return __uint_as_float(packed & 0xffff0000u);
}

// ---------------- CSR build ----------------

__global__ void count_deg(const int* __restrict__ dst, int* __restrict__ deg, int E) {
    int e = blockIdx.x * 256 + threadIdx.x;
    if (e < E) atomicAdd(&deg[dst[e]], 1);
}

__global__ void scan1(const int* __restrict__ deg, int* __restrict__ rowptr,
                      int* __restrict__ bsum, int n) {
    __shared__ int s[256];
    int t = threadIdx.x;
    int i = blockIdx.x * 256 + t;
    int v = (i < n) ? deg[i] : 0;
    s[t] = v;
    __syncthreads();
    for (int o = 1; o < 256; o <<= 1) {
        int add = (t >= o) ? s[t - o] : 0;
        __syncthreads();
        s[t] += add;
        __syncthreads();
    }
    if (i < n) rowptr[i] = s[t] - v;
    if (t == 255) bsum[blockIdx.x] = s[255];
}

__global__ void scan2(const int* __restrict__ bsum, int* __restrict__ boff, int nb) {
    __shared__ int s[512];
    int t = threadIdx.x;
    int v = (t < nb) ? bsum[t] : 0;
    s[t] = v;
    __syncthreads();
    for (int o = 1; o < 512; o <<= 1) {
        int add = (t >= o) ? s[t - o] : 0;
        __syncthreads();
        s[t] += add;
        __syncthreads();
    }
    if (t < nb) boff[t] = s[t] - v;
}

__global__ void scan3(int* __restrict__ rowptr, const int* __restrict__ boff,
                      int* __restrict__ cursor, int n) {
    int i = blockIdx.x * 256 + threadIdx.x;
    if (i < n) {
        int v = rowptr[i] + boff[blockIdx.x];
        rowptr[i] = v;
        cursor[i] = v;
    }
}

__global__ void dinv_k(const int* __restrict__ deg, float* __restrict__ dinv, int n) {
    int i = blockIdx.x * 256 + threadIdx.x;
    if (i < n) dinv[i] = rsqrtf((float)(deg[i] + 2));  // +2 self-loops
}

__global__ __launch_bounds__(256) void part1(
    const int* __restrict__ src, const int* __restrict__ dst,
    const int* __restrict__ rowptr, int* __restrict__ bcur,
    int2* __restrict__ pairBuf, int E, int NB) {
    __shared__ int hist[512];
    __shared__ int base[512];
    int t = threadIdx.x;
    int e0 = blockIdx.x * PB;
    int cnt = min(PB, E - e0);
    for (int b = t; b < NB; b += 256) hist[b] = 0;
    __syncthreads();
    for (int i = t; i < cnt; i += 256)
        atomicAdd(&hist[dst[e0 + i] >> BSH], 1);
    __syncthreads();
    for (int b = t; b < NB; b += 256) {
        int h = hist[b];
        int gb = (h > 0) ? atomicAdd(&bcur[b], h) : 0;
        base[b] = rowptr[b << BSH] + gb;
        hist[b] = 0;
    }
    __syncthreads();
    for (int i = t; i < cnt; i += 256) {
        int s = src[e0 + i], d = dst[e0 + i];
        int b = d >> BSH;
        int p = base[b] + atomicAdd(&hist[b], 1);
        pairBuf[p] = make_int2(s, d);
    }
}

__global__ __launch_bounds__(256) void part2(
    const int2* __restrict__ pairBuf, const int* __restrict__ rowptr,
    int* __restrict__ cursor, int* __restrict__ csr, int E, int N) {
    int b = blockIdx.x;
    int start = rowptr[b << BSH];
    int hi = (b + 1) << BSH;
    int end = (hi < N) ? rowptr[hi] : E;
    for (int i = start + threadIdx.x; i < end; i += 256) {
        int2 p = pairBuf[i];
        int q = atomicAdd(&cursor[p.y], 1);
        csr[q] = p.x;
    }
}

// ---------------- Weight transpose + bf16 convert (one-shot) ----------------
// W [K][OUT] fp32  ->  Wt [OUT][K] bf16 (B-fragment wants contiguous K)

__global__ void wtrans(const float* __restrict__ W1, const float* __restrict__ W2,
                       unsigned short* __restrict__ W1t, unsigned short* __restrict__ W2t) {
    int t = blockIdx.x * 256 + threadIdx.x;
    if (t < 128 * 128) {
        int nc = t >> 7, k = t & 127;
        W1t[t] = f2bf(W1[k * 128 + nc]);
    }
    int u = t - 128 * 128;
    if (u >= 0 && u < 64 * 128) {
        int nc = u >> 7, k = u & 127;
        W2t[u] = f2bf(W2[k * 64 + nc]);
    }
}

// ---------------- MFMA GEMM: C[n,OUT] = A[n,128] @ W[128,OUT], bf16 in, fp32 acc ---
// 128-row tile, 4 waves x 32 rows. Full Wt in LDS; A staged in two half-K chunks.
// Fragment layouts (m89/m91-verified): A[m=lane&15][k=quad*8+j],
// B[k=quad*8+j][n=lane&15], C/D col=lane&15 row=quad*4+reg.

template <int OUT, bool AFP32>
__global__ __launch_bounds__(256) void gemm_mfma(
    const void* __restrict__ Av, const unsigned short* __restrict__ Wt,
    unsigned short* __restrict__ C, int n) {
    constexpr int AP = 72;    // A chunk pitch (64+8) -> 2-way-free frag reads
    constexpr int WP = 136;   // W pitch (128+8)
    constexpr int NT = OUT / 16;
    __shared__ unsigned short As[128 * AP];
    __shared__ unsigned short Ws[OUT * WP];

    const int t = threadIdx.x;
    const int row0 = blockIdx.x * 128;

    // stage full Wt (bf16 [OUT][128], rows 256B): uint4 = 8 bf16
    for (int i = t; i < OUT * 16; i += 256) {
        int rr = i >> 4, sq = i & 15;
        *(uint4*)&Ws[rr * WP + sq * 8] = *(const uint4*)(Wt + rr * 128 + sq * 8);
    }

    const int w = t >> 6, l = t & 63;
    const int q = l >> 4, r16 = l & 15;
    const int mbase = w * 32;

    f32x4 acc0[NT], acc1[NT];
    for (int i = 0; i < NT; i++) {
        acc0[i] = (f32x4){0.f, 0.f, 0.f, 0.f};
        acc1[i] = (f32x4){0.f, 0.f, 0.f, 0.f};
    }

    for (int half = 0; half < 2; half++) {
        if (half) __syncthreads();            // As reuse
        if (AFP32) {
            const float* A = (const float*)Av;
            for (int i = t; i < 128 * 16; i += 256) {
                int rr = i >> 4, fq = i & 15;
                float4 v = make_float4(0.f, 0.f, 0.f, 0.f);
                if (row0 + rr < n)
                    v = *(const float4*)(A + (size_t)(row0 + rr) * 128 + half * 64 + fq * 4);
                unsigned short* p = &As[rr * AP + fq * 4];
                p[0] = f2bf(v.x); p[1] = f2bf(v.y); p[2] = f2bf(v.z); p[3] = f2bf(v.w);
            }
        } else {
            const unsigned short* A = (const unsigned short*)Av;
            for (int i = t; i < 128 * 8; i += 256) {
                int rr = i >> 3, sq = i & 7;
                uint4 v = make_uint4(0, 0, 0, 0);
                if (row0 + rr < n)
                    v = *(const uint4*)(A + (size_t)(row0 + rr) * 128 + half * 64 + sq * 8);
                *(uint4*)&As[rr * AP + sq * 8] = v;
            }
        }
        __syncthreads();

#pragma unroll
        for (int kc = 0; kc < 2; kc++) {
            int ko = kc * 32 + q * 8;             // within A chunk
            int kow = half * 64 + ko;             // within full-K Wt
            bf16x8 a0 = *(const bf16x8*)&As[(mbase + r16) * AP + ko];
            bf16x8 a1 = *(const bf16x8*)&As[(mbase + 16 + r16) * AP + ko];
#pragma unroll
            for (int nt = 0; nt < NT; nt++) {
                bf16x8 b = *(const bf16x8*)&Ws[(nt * 16 + r16) * WP + kow];
                acc0[nt] = __builtin_amdgcn_mfma_f32_16x16x32_bf16(a0, b, acc0[nt], 0, 0, 0);
                acc1[nt] = __builtin_amdgcn_mfma_f32_16x16x32_bf16(a1, b, acc1[nt], 0, 0, 0);
            }
        }
    }

#pragma unroll
    for (int nt = 0; nt < NT; nt++) {
#pragma unroll
        for (int p = 0; p < 4; p++) {
            int rr = row0 + mbase + q * 4 + p;
            if (rr < n) C[(size_t)rr * OUT + nt * 16 + r16] = f2bf(acc0[nt][p]);
            if (rr + 16 < n) C[(size_t)(rr + 16) * OUT + nt * 16 + r16] = f2bf(acc1[nt][p]);
        }
    }
}

// ---------------- Aggregation (one wave per node, 4-way edge ILP, bf16 gather) ----

__global__ __launch_bounds__(256) void agg_relu_128(
    const unsigned short* __restrict__ H, const int* __restrict__ csr,
    const int* __restrict__ rowptr, const int* __restrict__ deg,
    const float* __restrict__ dinv, const float* __restrict__ bias,
    unsigned short* __restrict__ out, int n) {
    int v = blockIdx.x * 4 + (threadIdx.x >> 6);
    if (v >= n) return;
    int lane = threadIdx.x & 63;
    int base = rowptr[v], cnt = deg[v];
    float2 a0 = make_float2(0.f, 0.f), a1 = a0, a2 = a0, a3 = a0;
    for (int j0 = 0; j0 < cnt; j0 += 64) {
        int nj = min(64, cnt - j0);
        int ul = 0; float wl = 0.f;
        if (lane < nj) { ul = csr[base + j0 + lane]; wl = dinv[ul]; }
        int j = 0;
        for (; j + 4 <= nj; j += 4) {
            int u0 = __shfl(ul, j),     u1 = __shfl(ul, j + 1);
            int u2 = __shfl(ul, j + 2), u3 = __shfl(ul, j + 3);
            float w0 = __shfl(wl, j),     w1 = __shfl(wl, j + 1);
            float w2 = __shfl(wl, j + 2), w3 = __shfl(wl, j + 3);
            uint32 h0 = *(const uint32*)(H + (size_t)u0 * 128 + lane * 2);
            uint32 h1 = *(const uint32*)(H + (size_t)u1 * 128 + lane * 2);
            uint32 h2 = *(const uint32*)(H + (size_t)u2 * 128 + lane * 2);
            uint32 h3 = *(const uint32*)(H + (size_t)u3 * 128 + lane * 2);
            a0.x += w0 * bflo(h0); a0.y += w0 * bfhi(h0);
            a1.x += w1 * bflo(h1); a1.y += w1 * bfhi(h1);
            a2.x += w2 * bflo(h2); a2.y += w2 * bfhi(h2);
            a3.x += w3 * bflo(h3); a3.y += w3 * bfhi(h3);
        }
        for (; j < nj; j++) {
            int u = __shfl(ul, j);
            float w = __shfl(wl, j);
            uint32 hv = *(const uint32*)(H + (size_t)u * 128 + lane * 2);
            a0.x += w * bflo(hv); a0.y += w * bfhi(hv);
        }
    }
    float2 acc = make_float2((a0.x + a1.x) + (a2.x + a3.x),
                             (a0.y + a1.y) + (a2.y + a3.y));
    float dv = dinv[v];
    float sl = 2.f * dv * dv;
    uint32 hv = *(const uint32*)(H + (size_t)v * 128 + lane * 2);
    float2 bb = ((const float2*)bias)[lane];
    float o0 = fmaxf(dv * acc.x + sl * bflo(hv) + bb.x, 0.f);
    float o1 = fmaxf(dv * acc.y + sl * bfhi(hv) + bb.y, 0.f);
    ((uint32*)out)[(size_t)v * 64 + lane] =
        (uint32)f2bf(o0) | ((uint32)f2bf(o1) << 16);
}

__global__ __launch_bounds__(256) void agg_lsm_64(
    const unsigned short* __restrict__ H, const int* __restrict__ csr,
    const int* __restrict__ rowptr, const int* __restrict__ deg,
    const float* __restrict__ dinv, const float* __restrict__ bias,
    float* __restrict__ out, int n) {
    int v = blockIdx.x * 4 + (threadIdx.x >> 6);
    if (v >= n) return;
    int lane = threadIdx.x & 63;
    int base = rowptr[v], cnt = deg[v];
    float a0 = 0.f, a1 = 0.f, a2 = 0.f, a3 = 0.f;
    for (int j0 = 0; j0 < cnt; j0 += 64) {
        int nj = min(64, cnt - j0);
        int ul = 0; float wl = 0.f;
        if (lane < nj) { ul = csr[base + j0 + lane]; wl = dinv[ul]; }
        int j = 0;
        for (; j + 4 <= nj; j += 4) {
            int u0 = __shfl(ul, j),     u1 = __shfl(ul, j + 1);
            int u2 = __shfl(ul, j + 2), u3 = __shfl(ul, j + 3);
            float w0 = __shfl(wl, j),     w1 = __shfl(wl, j + 1);
            float w2 = __shfl(wl, j + 2), w3 = __shfl(wl, j + 3);
            float h0 = __uint_as_float((uint32)H[(size_t)u0 * 64 + lane] << 16);
            float h1 = __uint_as_float((uint32)H[(size_t)u1 * 64 + lane] << 16);
            float h2 = __uint_as_float((uint32)H[(size_t)u2 * 64 + lane] << 16);
            float h3 = __uint_as_float((uint32)H[(size_t)u3 * 64 + lane] << 16);
            a0 += w0 * h0; a1 += w1 * h1; a2 += w2 * h2; a3 += w3 * h3;
        }
        for (; j < nj; j++) {
            int u = __shfl(ul, j);
            float w = __shfl(wl, j);
            a0 += w * __uint_as_float((uint32)H[(size_t)u * 64 + lane] << 16);
        }
    }
    float acc = (a0 + a1) + (a2 + a3);
    float dv = dinv[v];
    float hv = __uint_as_float((uint32)H[(size_t)v * 64 + lane] << 16);
    float val = dv * acc + 2.f * dv * dv * hv + bias[lane];
    float m = val;
    for (int o = 32; o > 0; o >>= 1) m = fmaxf(m, __shfl_xor(m, o));
    float e = __expf(val - m);
    float ssum = e;
    for (int o = 32; o > 0; o >>= 1) ssum += __shfl_xor(ssum, o);
    out[(size_t)v * 64 + lane] = val - m - __logf(ssum);
}

// ---------------- launch ----------------

extern "C" void kernel_launch(void* const* d_in, const int* in_sizes, int n_in,
                              void* d_out, int out_size, void* d_ws, size_t ws_size,
                              hipStream_t stream) {
    const float* x  = (const float*)d_in[0];
    const int*   ei = (const int*)d_in[1];
    const float* W1 = (const float*)d_in[2];
    const float* b1 = (const float*)d_in[3];
    const float* W2 = (const float*)d_in[4];
    const float* b2 = (const float*)d_in[5];
    float* out = (float*)d_out;

    const int N = in_sizes[0] / IN_CH;  // 100000
    const int E = in_sizes[1] / 2;      // 1600000
    const int* src = ei;
    const int* dst = ei + E;
    const int NB = (N + 255) >> BSH;    // 391 buckets

    char* w = (char*)d_ws;
    size_t off = 0;
    auto alloc = [&](size_t bytes) -> char* {
        char* p = w + off;
        off = (off + bytes + 255) & ~(size_t)255;
        return p;
    };
    int*   deg    = (int*)alloc((size_t)N * 4);
    int*   rowptr = (int*)alloc((size_t)N * 4);
    int*   cursor = (int*)alloc((size_t)N * 4);
    int*   bsum   = (int*)alloc(512 * 4);
    int*   boff   = (int*)alloc(512 * 4);
    int*   bcur   = (int*)alloc(512 * 4);
    float* dinv   = (float*)alloc((size_t)N * 4);
    int*   csr    = (int*)alloc((size_t)E * 4);
    unsigned short* W1t = (unsigned short*)alloc(128 * 128 * 2);
    unsigned short* W2t = (unsigned short*)alloc(64 * 128 * 2);
    unsigned short* H1  = (unsigned short*)alloc((size_t)N * HID_CH * 2);  // bf16
    unsigned short* A1b = (unsigned short*)alloc((size_t)N * HID_CH * 2);  // bf16
    unsigned short* H2  = H1;            // H1 dead after agg1
    int2*  pairBuf = (int2*)A1b;         // A1b not written until agg1 (after part2)

    hipMemsetAsync(deg, 0, (size_t)N * 4, stream);
    hipMemsetAsync(bcur, 0, 512 * 4, stream);

    int gE = (E + 255) / 256;
    int gN = (N + 255) / 256;

    wtrans<<<96, 256, 0, stream>>>(W1, W2, W1t, W2t);
    count_deg<<<gE, 256, 0, stream>>>(dst, deg, E);
    scan1<<<gN, 256, 0, stream>>>(deg, rowptr, bsum, N);
    scan2<<<1, 512, 0, stream>>>(bsum, boff, gN);
    scan3<<<gN, 256, 0, stream>>>(rowptr, boff, cursor, N);
    dinv_k<<<gN, 256, 0, stream>>>(deg, dinv, N);
    part1<<<(E + PB - 1) / PB, 256, 0, stream>>>(src, dst, rowptr, bcur, pairBuf, E, NB);
    part2<<<NB, 256, 0, stream>>>(pairBuf, rowptr, cursor, csr, E, N);

    gemm_mfma<128, true><<<(N + 127) / 128, 256, 0, stream>>>(x, W1t, H1, N);
    agg_relu_128<<<(N + 3) / 4, 256, 0, stream>>>(H1, csr, rowptr, deg, dinv, b1, A1b, N);
    gemm_mfma<64, false><<<(N + 127) / 128, 256, 0, stream>>>(A1b, W2t, H2, N);
    agg_lsm_64<<<(N + 3) / 4, 256, 0, stream>>>(H2, csr, rowptr, deg, dinv, b2, out, N);
}

// Round 6
// 384.914 us; speedup vs baseline: 1.6327x; 1.0376x over previous
//
#include <hip/hip_runtime.h>
#include <cstdint>
#include <cstddef>

#define IN_CH 128
#define HID_CH 128
#define OUT_CH 64
#define BSH 8        // nodes per bucket = 256
#define PB 4096      // edges per part1 block

typedef unsigned int uint32;
typedef unsigned char uchar;
typedef short bf16x8 __attribute__((ext_vector_type(8)));
typedef float f32x4 __attribute__((ext_vector_type(4)));
typedef float f32x2 __attribute__((ext_vector_type(2)));

// float -> bf16 round-to-nearest-even
static __device__ __forceinline__ unsigned short f2bf(float f) {
    uint32 u = __float_as_uint(f);
    u += 0x7fffu + ((u >> 16) & 1u);
    return (unsigned short)(u >> 16);
}
// float -> fp8 e4m3 (OCP) single byte via HW cvt
static __device__ __forceinline__ uchar f2fp8(float f) {
    int p = __builtin_amdgcn_cvt_pk_fp8_f32(f, f, 0, false);
    return (uchar)(p & 0xff);
}

// ---------------- CSR build ----------------

__global__ void count_deg(const int* __restrict__ dst, int* __restrict__ deg, int E) {
    int e = blockIdx.x * 256 + threadIdx.x;
    if (e < E) atomicAdd(&deg[dst[e]], 1);
}

__global__ void scan1(const int* __restrict__ deg, int* __restrict__ rowptr,
                      int* __restrict__ bsum, int n) {
    __shared__ int s[256];
    int t = threadIdx.x;
    int i = blockIdx.x * 256 + t;
    int v = (i < n) ? deg[i] : 0;
    s[t] = v;
    __syncthreads();
    for (int o = 1; o < 256; o <<= 1) {
        int add = (t >= o) ? s[t - o] : 0;
        __syncthreads();
        s[t] += add;
        __syncthreads();
    }
    if (i < n) rowptr[i] = s[t] - v;
    if (t == 255) bsum[blockIdx.x] = s[255];
}

__global__ void scan2(const int* __restrict__ bsum, int* __restrict__ boff, int nb) {
    __shared__ int s[512];
    int t = threadIdx.x;
    int v = (t < nb) ? bsum[t] : 0;
    s[t] = v;
    __syncthreads();
    for (int o = 1; o < 512; o <<= 1) {
        int add = (t >= o) ? s[t - o] : 0;
        __syncthreads();
        s[t] += add;
        __syncthreads();
    }
    if (t < nb) boff[t] = s[t] - v;
}

__global__ void scan3(int* __restrict__ rowptr, const int* __restrict__ boff,
                      int* __restrict__ cursor, int n) {
    int i = blockIdx.x * 256 + threadIdx.x;
    if (i < n) {
        int v = rowptr[i] + boff[blockIdx.x];
        rowptr[i] = v;
        cursor[i] = v;
    }
}

__global__ void dinv_k(const int* __restrict__ deg, float* __restrict__ dinv, int n) {
    int i = blockIdx.x * 256 + threadIdx.x;
    if (i < n) dinv[i] = rsqrtf((float)(deg[i] + 2));  // +2 self-loops
}

__global__ __launch_bounds__(256) void part1(
    const int* __restrict__ src, const int* __restrict__ dst,
    const int* __restrict__ rowptr, int* __restrict__ bcur,
    int2* __restrict__ pairBuf, int E, int NB) {
    __shared__ int hist[512];
    __shared__ int base[512];
    int t = threadIdx.x;
    int e0 = blockIdx.x * PB;
    int cnt = min(PB, E - e0);
    for (int b = t; b < NB; b += 256) hist[b] = 0;
    __syncthreads();
    for (int i = t; i < cnt; i += 256)
        atomicAdd(&hist[dst[e0 + i] >> BSH], 1);
    __syncthreads();
    for (int b = t; b < NB; b += 256) {
        int h = hist[b];
        int gb = (h > 0) ? atomicAdd(&bcur[b], h) : 0;
        base[b] = rowptr[b << BSH] + gb;
        hist[b] = 0;
    }
    __syncthreads();
    for (int i = t; i < cnt; i += 256) {
        int s = src[e0 + i], d = dst[e0 + i];
        int b = d >> BSH;
        int p = base[b] + atomicAdd(&hist[b], 1);
        pairBuf[p] = make_int2(s, d);
    }
}

__global__ __launch_bounds__(256) void part2(
    const int2* __restrict__ pairBuf, const int* __restrict__ rowptr,
    int* __restrict__ cursor, int* __restrict__ csr, int E, int N) {
    int b = blockIdx.x;
    int start = rowptr[b << BSH];
    int hi = (b + 1) << BSH;
    int end = (hi < N) ? rowptr[hi] : E;
    for (int i = start + threadIdx.x; i < end; i += 256) {
        int2 p = pairBuf[i];
        int q = atomicAdd(&cursor[p.y], 1);
        csr[q] = p.x;
    }
}

// ---------------- Weight transpose + bf16 convert (one-shot) ----------------

__global__ void wtrans(const float* __restrict__ W1, const float* __restrict__ W2,
                       unsigned short* __restrict__ W1t, unsigned short* __restrict__ W2t) {
    int t = blockIdx.x * 256 + threadIdx.x;
    if (t < 128 * 128) {
        int nc = t >> 7, k = t & 127;
        W1t[t] = f2bf(W1[k * 128 + nc]);
    }
    int u = t - 128 * 128;
    if (u >= 0 && u < 64 * 128) {
        int nc = u >> 7, k = u & 127;
        W2t[u] = f2bf(W2[k * 64 + nc]);
    }
}

// ---------------- MFMA GEMM: C[n,OUT] = A[n,128] @ W[128,OUT] -> fp8 out ----------
// bf16 inputs, fp32 acc, fp8 e4m3 output (gather side wants minimal bytes).
// Fragment layouts (m89/m91-verified): A[m=lane&15][k=quad*8+j],
// B[k=quad*8+j][n=lane&15], C/D col=lane&15 row=quad*4+reg.

template <int OUT, bool AFP32>
__global__ __launch_bounds__(256) void gemm_mfma(
    const void* __restrict__ Av, const unsigned short* __restrict__ Wt,
    uchar* __restrict__ C, int n) {
    constexpr int AP = 72;    // A chunk pitch (64+8)
    constexpr int WP = 136;   // W pitch (128+8)
    constexpr int NT = OUT / 16;
    __shared__ unsigned short As[128 * AP];
    __shared__ unsigned short Ws[OUT * WP];

    const int t = threadIdx.x;
    const int row0 = blockIdx.x * 128;

    for (int i = t; i < OUT * 16; i += 256) {
        int rr = i >> 4, sq = i & 15;
        *(uint4*)&Ws[rr * WP + sq * 8] = *(const uint4*)(Wt + rr * 128 + sq * 8);
    }

    const int w = t >> 6, l = t & 63;
    const int q = l >> 4, r16 = l & 15;
    const int mbase = w * 32;

    f32x4 acc0[NT], acc1[NT];
    for (int i = 0; i < NT; i++) {
        acc0[i] = (f32x4){0.f, 0.f, 0.f, 0.f};
        acc1[i] = (f32x4){0.f, 0.f, 0.f, 0.f};
    }

    for (int half = 0; half < 2; half++) {
        if (half) __syncthreads();
        if (AFP32) {
            const float* A = (const float*)Av;
            for (int i = t; i < 128 * 16; i += 256) {
                int rr = i >> 4, fq = i & 15;
                float4 v = make_float4(0.f, 0.f, 0.f, 0.f);
                if (row0 + rr < n)
                    v = *(const float4*)(A + (size_t)(row0 + rr) * 128 + half * 64 + fq * 4);
                unsigned short* p = &As[rr * AP + fq * 4];
                p[0] = f2bf(v.x); p[1] = f2bf(v.y); p[2] = f2bf(v.z); p[3] = f2bf(v.w);
            }
        } else {
            const unsigned short* A = (const unsigned short*)Av;
            for (int i = t; i < 128 * 8; i += 256) {
                int rr = i >> 3, sq = i & 7;
                uint4 v = make_uint4(0, 0, 0, 0);
                if (row0 + rr < n)
                    v = *(const uint4*)(A + (size_t)(row0 + rr) * 128 + half * 64 + sq * 8);
                *(uint4*)&As[rr * AP + sq * 8] = v;
            }
        }
        __syncthreads();

#pragma unroll
        for (int kc = 0; kc < 2; kc++) {
            int ko = kc * 32 + q * 8;
            int kow = half * 64 + ko;
            bf16x8 a0 = *(const bf16x8*)&As[(mbase + r16) * AP + ko];
            bf16x8 a1 = *(const bf16x8*)&As[(mbase + 16 + r16) * AP + ko];
#pragma unroll
            for (int nt = 0; nt < NT; nt++) {
                bf16x8 b = *(const bf16x8*)&Ws[(nt * 16 + r16) * WP + kow];
                acc0[nt] = __builtin_amdgcn_mfma_f32_16x16x32_bf16(a0, b, acc0[nt], 0, 0, 0);
                acc1[nt] = __builtin_amdgcn_mfma_f32_16x16x32_bf16(a1, b, acc1[nt], 0, 0, 0);
            }
        }
    }

#pragma unroll
    for (int nt = 0; nt < NT; nt++) {
#pragma unroll
        for (int p = 0; p < 4; p++) {
            int rr = row0 + mbase + q * 4 + p;
            if (rr < n) C[(size_t)rr * OUT + nt * 16 + r16] = f2fp8(acc0[nt][p]);
            if (rr + 16 < n) C[(size_t)(rr + 16) * OUT + nt * 16 + r16] = f2fp8(acc1[nt][p]);
        }
    }
}

// ---------------- Aggregation (one wave/node, 4-way edge ILP, fp8 gather) --------

__global__ __launch_bounds__(256) void agg_relu_128(
    const uchar* __restrict__ H, const int* __restrict__ csr,
    const int* __restrict__ rowptr, const int* __restrict__ deg,
    const float* __restrict__ dinv, const float* __restrict__ bias,
    unsigned short* __restrict__ out, int n) {
    int v = blockIdx.x * 4 + (threadIdx.x >> 6);
    if (v >= n) return;
    int lane = threadIdx.x & 63;
    int base = rowptr[v], cnt = deg[v];
    float2 a0 = make_float2(0.f, 0.f), a1 = a0, a2 = a0, a3 = a0;
    for (int j0 = 0; j0 < cnt; j0 += 64) {
        int nj = min(64, cnt - j0);
        int ul = 0; float wl = 0.f;
        if (lane < nj) { ul = csr[base + j0 + lane]; wl = dinv[ul]; }
        int j = 0;
        for (; j + 4 <= nj; j += 4) {
            int u0 = __shfl(ul, j),     u1 = __shfl(ul, j + 1);
            int u2 = __shfl(ul, j + 2), u3 = __shfl(ul, j + 3);
            float w0 = __shfl(wl, j),     w1 = __shfl(wl, j + 1);
            float w2 = __shfl(wl, j + 2), w3 = __shfl(wl, j + 3);
            int h0 = *(const unsigned short*)(H + (size_t)u0 * 128 + lane * 2);
            int h1 = *(const unsigned short*)(H + (size_t)u1 * 128 + lane * 2);
            int h2 = *(const unsigned short*)(H + (size_t)u2 * 128 + lane * 2);
            int h3 = *(const unsigned short*)(H + (size_t)u3 * 128 + lane * 2);
            f32x2 d0 = __builtin_amdgcn_cvt_pk_f32_fp8(h0, false);
            f32x2 d1 = __builtin_amdgcn_cvt_pk_f32_fp8(h1, false);
            f32x2 d2 = __builtin_amdgcn_cvt_pk_f32_fp8(h2, false);
            f32x2 d3 = __builtin_amdgcn_cvt_pk_f32_fp8(h3, false);
            a0.x += w0 * d0[0]; a0.y += w0 * d0[1];
            a1.x += w1 * d1[0]; a1.y += w1 * d1[1];
            a2.x += w2 * d2[0]; a2.y += w2 * d2[1];
            a3.x += w3 * d3[0]; a3.y += w3 * d3[1];
        }
        for (; j < nj; j++) {
            int u = __shfl(ul, j);
            float w = __shfl(wl, j);
            int hv = *(const unsigned short*)(H + (size_t)u * 128 + lane * 2);
            f32x2 d = __builtin_amdgcn_cvt_pk_f32_fp8(hv, false);
            a0.x += w * d[0]; a0.y += w * d[1];
        }
    }
    float2 acc = make_float2((a0.x + a1.x) + (a2.x + a3.x),
                             (a0.y + a1.y) + (a2.y + a3.y));
    float dv = dinv[v];
    float sl = 2.f * dv * dv;
    int hv = *(const unsigned short*)(H + (size_t)v * 128 + lane * 2);
    f32x2 dsl = __builtin_amdgcn_cvt_pk_f32_fp8(hv, false);
    float2 bb = ((const float2*)bias)[lane];
    float o0 = fmaxf(dv * acc.x + sl * dsl[0] + bb.x, 0.f);
    float o1 = fmaxf(dv * acc.y + sl * dsl[1] + bb.y, 0.f);
    ((uint32*)out)[(size_t)v * 64 + lane] =
        (uint32)f2bf(o0) | ((uint32)f2bf(o1) << 16);
}

__global__ __launch_bounds__(256) void agg_lsm_64(
    const uchar* __restrict__ H, const int* __restrict__ csr,
    const int* __restrict__ rowptr, const int* __restrict__ deg,
    const float* __restrict__ dinv, const float* __restrict__ bias,
    float* __restrict__ out, int n) {
    int v = blockIdx.x * 4 + (threadIdx.x >> 6);
    if (v >= n) return;
    int lane = threadIdx.x & 63;
    int base = rowptr[v], cnt = deg[v];
    float a0 = 0.f, a1 = 0.f, a2 = 0.f, a3 = 0.f;
    for (int j0 = 0; j0 < cnt; j0 += 64) {
        int nj = min(64, cnt - j0);
        int ul = 0; float wl = 0.f;
        if (lane < nj) { ul = csr[base + j0 + lane]; wl = dinv[ul]; }
        int j = 0;
        for (; j + 4 <= nj; j += 4) {
            int u0 = __shfl(ul, j),     u1 = __shfl(ul, j + 1);
            int u2 = __shfl(ul, j + 2), u3 = __shfl(ul, j + 3);
            float w0 = __shfl(wl, j),     w1 = __shfl(wl, j + 1);
            float w2 = __shfl(wl, j + 2), w3 = __shfl(wl, j + 3);
            int h0 = H[(size_t)u0 * 64 + lane];
            int h1 = H[(size_t)u1 * 64 + lane];
            int h2 = H[(size_t)u2 * 64 + lane];
            int h3 = H[(size_t)u3 * 64 + lane];
            a0 += w0 * __builtin_amdgcn_cvt_f32_fp8(h0, 0);
            a1 += w1 * __builtin_amdgcn_cvt_f32_fp8(h1, 0);
            a2 += w2 * __builtin_amdgcn_cvt_f32_fp8(h2, 0);
            a3 += w3 * __builtin_amdgcn_cvt_f32_fp8(h3, 0);
        }
        for (; j < nj; j++) {
            int u = __shfl(ul, j);
            float w = __shfl(wl, j);
            a0 += w * __builtin_amdgcn_cvt_f32_fp8((int)H[(size_t)u * 64 + lane], 0);
        }
    }
    float acc = (a0 + a1) + (a2 + a3);
    float dv = dinv[v];
    float hv = __builtin_amdgcn_cvt_f32_fp8((int)H[(size_t)v * 64 + lane], 0);
    float val = dv * acc + 2.f * dv * dv * hv + bias[lane];
    float m = val;
    for (int o = 32; o > 0; o >>= 1) m = fmaxf(m, __shfl_xor(m, o));
    float e = __expf(val - m);
    float ssum = e;
    for (int o = 32; o > 0; o >>= 1) ssum += __shfl_xor(ssum, o);
    out[(size_t)v * 64 + lane] = val - m - __logf(ssum);
}

// ---------------- launch ----------------

extern "C" void kernel_launch(void* const* d_in, const int* in_sizes, int n_in,
                              void* d_out, int out_size, void* d_ws, size_t ws_size,
                              hipStream_t stream) {
    const float* x  = (const float*)d_in[0];
    const int*   ei = (const int*)d_in[1];
    const float* W1 = (const float*)d_in[2];
    const float* b1 = (const float*)d_in[3];
    const float* W2 = (const float*)d_in[4];
    const float* b2 = (const float*)d_in[5];
    float* out = (float*)d_out;

    const int N = in_sizes[0] / IN_CH;  // 100000
    const int E = in_sizes[1] / 2;      // 1600000
    const int* src = ei;
    const int* dst = ei + E;
    const int NB = (N + 255) >> BSH;    // 391 buckets

    char* w = (char*)d_ws;
    size_t off = 0;
    auto alloc = [&](size_t bytes) -> char* {
        char* p = w + off;
        off = (off + bytes + 255) & ~(size_t)255;
        return p;
    };
    int*   deg    = (int*)alloc((size_t)N * 4);
    int*   rowptr = (int*)alloc((size_t)N * 4);
    int*   cursor = (int*)alloc((size_t)N * 4);
    int*   bsum   = (int*)alloc(512 * 4);
    int*   boff   = (int*)alloc(512 * 4);
    int*   bcur   = (int*)alloc(512 * 4);
    float* dinv   = (float*)alloc((size_t)N * 4);
    int*   csr    = (int*)alloc((size_t)E * 4);
    unsigned short* W1t = (unsigned short*)alloc(128 * 128 * 2);
    unsigned short* W2t = (unsigned short*)alloc(64 * 128 * 2);
    uchar* H1  = (uchar*)alloc((size_t)N * HID_CH);          // fp8, 12.8 MB
    unsigned short* A1b = (unsigned short*)alloc((size_t)N * HID_CH * 2);  // bf16
    uchar* H2  = H1;                     // fp8, 6.4 MB; H1 dead after agg1
    int2*  pairBuf = (int2*)A1b;         // A1b not written until agg1 (after part2)

    hipMemsetAsync(deg, 0, (size_t)N * 4, stream);
    hipMemsetAsync(bcur, 0, 512 * 4, stream);

    int gE = (E + 255) / 256;
    int gN = (N + 255) / 256;

    wtrans<<<96, 256, 0, stream>>>(W1, W2, W1t, W2t);
    count_deg<<<gE, 256, 0, stream>>>(dst, deg, E);
    scan1<<<gN, 256, 0, stream>>>(deg, rowptr, bsum, N);
    scan2<<<1, 512, 0, stream>>>(bsum, boff, gN);
    scan3<<<gN, 256, 0, stream>>>(rowptr, boff, cursor, N);
    dinv_k<<<gN, 256, 0, stream>>>(deg, dinv, N);
    part1<<<(E + PB - 1) / PB, 256, 0, stream>>>(src, dst, rowptr, bcur, pairBuf, E, NB);
    part2<<<NB, 256, 0, stream>>>(pairBuf, rowptr, cursor, csr, E, N);

    gemm_mfma<128, true><<<(N + 127) / 128, 256, 0, stream>>>(x, W1t, H1, N);
    agg_relu_128<<<(N + 3) / 4, 256, 0, stream>>>(H1, csr, rowptr, deg, dinv, b1, A1b, N);
    gemm_mfma<64, false><<<(N + 127) / 128, 256, 0, stream>>>(A1b, W2t, H2, N);
    agg_lsm_64<<<(N + 3) / 4, 256, 0, stream>>>(H2, csr, rowptr, deg, dinv, b2, out, N);
}

// Round 8
// 300.782 us; speedup vs baseline: 2.0894x; 1.2797x over previous
//
#include <hip/hip_runtime.h>
#include <cstdint>
#include <cstddef>

#define IN_CH 128
#define HID_CH 128
#define OUT_CH 64
#define BSH 8        // nodes per bucket = 256
#define PB 4096      // edges per histogram/partition block

typedef unsigned int uint32;
typedef unsigned char uchar;
typedef short bf16x8 __attribute__((ext_vector_type(8)));
typedef float f32x4 __attribute__((ext_vector_type(4)));
typedef float f32x2 __attribute__((ext_vector_type(2)));

// float -> bf16 round-to-nearest-even
static __device__ __forceinline__ unsigned short f2bf(float f) {
    uint32 u = __float_as_uint(f);
    u += 0x7fffu + ((u >> 16) & 1u);
    return (unsigned short)(u >> 16);
}
// float -> fp8 e4m3 (OCP) single byte via HW cvt
static __device__ __forceinline__ uchar f2fp8(float f) {
    int p = __builtin_amdgcn_cvt_pk_fp8_f32(f, f, 0, false);
    return (uchar)(p & 0xff);
}

// ---------------- CSR build (bucketed, LDS-atomic only) ----------------

// Per-block LDS histogram over buckets; one global atomic per (block,bucket).
__global__ __launch_bounds__(256) void bhist(const int* __restrict__ dst,
                                             int* __restrict__ bcnt, int E, int NB) {
    __shared__ int h[512];
    int t = threadIdx.x;
    int e0 = blockIdx.x * PB;
    int cnt = min(PB, E - e0);
    for (int b = t; b < NB; b += 256) h[b] = 0;
    __syncthreads();
    for (int i = t; i < cnt; i += 256)
        atomicAdd(&h[dst[e0 + i] >> BSH], 1);
    __syncthreads();
    for (int b = t; b < NB; b += 256)
        if (h[b]) atomicAdd(&bcnt[b], h[b]);
}

// Single-block exclusive scan of bucket counts -> bases; cursors start at ZERO
// (part1 adds bbase[b] itself -- R7's crash was bcur[t]=bbase[t] double-count).
__global__ void bscan(const int* __restrict__ bcnt, int* __restrict__ bbase,
                      int* __restrict__ bcur, int NB, int E) {
    __shared__ int s[512];
    int t = threadIdx.x;
    int v = (t < NB) ? bcnt[t] : 0;
    s[t] = v;
    __syncthreads();
    for (int o = 1; o < 512; o <<= 1) {
        int add = (t >= o) ? s[t - o] : 0;
        __syncthreads();
        s[t] += add;
        __syncthreads();
    }
    if (t < NB) { bbase[t] = s[t] - v; bcur[t] = 0; }
    if (t == 0) bbase[NB] = E;
}

// Partition edges into bucket runs (dense writes per block-bucket run).
__global__ __launch_bounds__(256) void part1(
    const int* __restrict__ src, const int* __restrict__ dst,
    const int* __restrict__ bbase, int* __restrict__ bcur,
    int2* __restrict__ pairBuf, int E, int NB) {
    __shared__ int hist[512];
    __shared__ int base[512];
    int t = threadIdx.x;
    int e0 = blockIdx.x * PB;
    int cnt = min(PB, E - e0);
    for (int b = t; b < NB; b += 256) hist[b] = 0;
    __syncthreads();
    for (int i = t; i < cnt; i += 256)
        atomicAdd(&hist[dst[e0 + i] >> BSH], 1);
    __syncthreads();
    for (int b = t; b < NB; b += 256) {
        int h = hist[b];
        int gb = (h > 0) ? atomicAdd(&bcur[b], h) : 0;
        base[b] = bbase[b] + gb;
        hist[b] = 0;
    }
    __syncthreads();
    for (int i = t; i < cnt; i += 256) {
        int s = src[e0 + i], d = dst[e0 + i];
        int b = d >> BSH;
        int p = base[b] + atomicAdd(&hist[b], 1);
        pairBuf[p] = make_int2(s, d);
    }
}

// One block per bucket: per-node degree in LDS, LDS scan -> rowptr/deg/dinv,
// LDS-cursor scatter of csr into the bucket's contiguous window.
__global__ __launch_bounds__(256) void bucket_build(
    const int2* __restrict__ pairBuf, const int* __restrict__ bbase,
    int* __restrict__ rowptr, int* __restrict__ deg, float* __restrict__ dinv,
    int* __restrict__ csr, int N) {
    __shared__ int cnt[256];
    __shared__ int loc[256];
    int b = blockIdx.x, t = threadIdx.x;
    int start = bbase[b], end = bbase[b + 1];
    cnt[t] = 0;
    __syncthreads();
    for (int i = start + t; i < end; i += 256)
        atomicAdd(&cnt[pairBuf[i].y & 255], 1);
    __syncthreads();
    int v = cnt[t];
    loc[t] = v;
    __syncthreads();
    for (int o = 1; o < 256; o <<= 1) {
        int add = (t >= o) ? loc[t - o] : 0;
        __syncthreads();
        loc[t] += add;
        __syncthreads();
    }
    int excl = loc[t] - v;
    int node = (b << BSH) + t;
    if (node < N) {
        rowptr[node] = start + excl;
        deg[node] = v;
        dinv[node] = rsqrtf((float)(v + 2));   // +2 self-loops
    }
    __syncthreads();
    cnt[t] = excl;                              // reuse as cursor
    __syncthreads();
    for (int i = start + t; i < end; i += 256) {
        int2 p = pairBuf[i];
        int q = start + atomicAdd(&cnt[p.y & 255], 1);
        csr[q] = p.x;
    }
}

// ---------------- Weight transpose + bf16 convert (one-shot) ----------------

__global__ void wtrans(const float* __restrict__ W1, const float* __restrict__ W2,
                       unsigned short* __restrict__ W1t, unsigned short* __restrict__ W2t) {
    int t = blockIdx.x * 256 + threadIdx.x;
    if (t < 128 * 128) {
        int nc = t >> 7, k = t & 127;
        W1t[t] = f2bf(W1[k * 128 + nc]);
    }
    int u = t - 128 * 128;
    if (u >= 0 && u < 64 * 128) {
        int nc = u >> 7, k = u & 127;
        W2t[u] = f2bf(W2[k * 64 + nc]);
    }
}

// ---------------- MFMA GEMM: C[n,OUT] = A[n,128] @ W[128,OUT] -> fp8 out ----------
// bf16 inputs, fp32 acc, fp8 e4m3 output. Fragment layouts (m89/m91-verified):
// A[m=lane&15][k=quad*8+j], B[k=quad*8+j][n=lane&15], C/D col=lane&15 row=quad*4+reg.

template <int OUT, bool AFP32>
__global__ __launch_bounds__(256) void gemm_mfma(
    const void* __restrict__ Av, const unsigned short* __restrict__ Wt,
    uchar* __restrict__ C, int n) {
    constexpr int AP = 72;    // A chunk pitch (64+8)
    constexpr int WP = 136;   // W pitch (128+8)
    constexpr int NT = OUT / 16;
    __shared__ unsigned short As[128 * AP];
    __shared__ unsigned short Ws[OUT * WP];

    const int t = threadIdx.x;
    const int row0 = blockIdx.x * 128;

    for (int i = t; i < OUT * 16; i += 256) {
        int rr = i >> 4, sq = i & 15;
        *(uint4*)&Ws[rr * WP + sq * 8] = *(const uint4*)(Wt + rr * 128 + sq * 8);
    }

    const int w = t >> 6, l = t & 63;
    const int q = l >> 4, r16 = l & 15;
    const int mbase = w * 32;

    f32x4 acc0[NT], acc1[NT];
    for (int i = 0; i < NT; i++) {
        acc0[i] = (f32x4){0.f, 0.f, 0.f, 0.f};
        acc1[i] = (f32x4){0.f, 0.f, 0.f, 0.f};
    }

    for (int half = 0; half < 2; half++) {
        if (half) __syncthreads();
        if (AFP32) {
            const float* A = (const float*)Av;
            for (int i = t; i < 128 * 16; i += 256) {
                int rr = i >> 4, fq = i & 15;
                float4 v = make_float4(0.f, 0.f, 0.f, 0.f);
                if (row0 + rr < n)
                    v = *(const float4*)(A + (size_t)(row0 + rr) * 128 + half * 64 + fq * 4);
                unsigned short* p = &As[rr * AP + fq * 4];
                p[0] = f2bf(v.x); p[1] = f2bf(v.y); p[2] = f2bf(v.z); p[3] = f2bf(v.w);
            }
        } else {
            const unsigned short* A = (const unsigned short*)Av;
            for (int i = t; i < 128 * 8; i += 256) {
                int rr = i >> 3, sq = i & 7;
                uint4 v = make_uint4(0, 0, 0, 0);
                if (row0 + rr < n)
                    v = *(const uint4*)(A + (size_t)(row0 + rr) * 128 + half * 64 + sq * 8);
                *(uint4*)&As[rr * AP + sq * 8] = v;
            }
        }
        __syncthreads();

#pragma unroll
        for (int kc = 0; kc < 2; kc++) {
            int ko = kc * 32 + q * 8;
            int kow = half * 64 + ko;
            bf16x8 a0 = *(const bf16x8*)&As[(mbase + r16) * AP + ko];
            bf16x8 a1 = *(const bf16x8*)&As[(mbase + 16 + r16) * AP + ko];
#pragma unroll
            for (int nt = 0; nt < NT; nt++) {
                bf16x8 b = *(const bf16x8*)&Ws[(nt * 16 + r16) * WP + kow];
                acc0[nt] = __builtin_amdgcn_mfma_f32_16x16x32_bf16(a0, b, acc0[nt], 0, 0, 0);
                acc1[nt] = __builtin_amdgcn_mfma_f32_16x16x32_bf16(a1, b, acc1[nt], 0, 0, 0);
            }
        }
    }

#pragma unroll
    for (int nt = 0; nt < NT; nt++) {
#pragma unroll
        for (int p = 0; p < 4; p++) {
            int rr = row0 + mbase + q * 4 + p;
            if (rr < n) C[(size_t)rr * OUT + nt * 16 + r16] = f2fp8(acc0[nt][p]);
            if (rr + 16 < n) C[(size_t)(rr + 16) * OUT + nt * 16 + r16] = f2fp8(acc1[nt][p]);
        }
    }
}

// ---------------- Aggregation (one wave/node, 4-way edge ILP, fp8 gather) --------

__global__ __launch_bounds__(256) void agg_relu_128(
    const uchar* __restrict__ H, const int* __restrict__ csr,
    const int* __restrict__ rowptr, const int* __restrict__ deg,
    const float* __restrict__ dinv, const float* __restrict__ bias,
    unsigned short* __restrict__ out, int n) {
    int v = blockIdx.x * 4 + (threadIdx.x >> 6);
    if (v >= n) return;
    int lane = threadIdx.x & 63;
    int base = rowptr[v], cnt = deg[v];
    float2 a0 = make_float2(0.f, 0.f), a1 = a0, a2 = a0, a3 = a0;
    for (int j0 = 0; j0 < cnt; j0 += 64) {
        int nj = min(64, cnt - j0);
        int ul = 0; float wl = 0.f;
        if (lane < nj) { ul = csr[base + j0 + lane]; wl = dinv[ul]; }
        int j = 0;
        for (; j + 4 <= nj; j += 4) {
            int u0 = __shfl(ul, j),     u1 = __shfl(ul, j + 1);
            int u2 = __shfl(ul, j + 2), u3 = __shfl(ul, j + 3);
            float w0 = __shfl(wl, j),     w1 = __shfl(wl, j + 1);
            float w2 = __shfl(wl, j + 2), w3 = __shfl(wl, j + 3);
            int h0 = *(const unsigned short*)(H + (size_t)u0 * 128 + lane * 2);
            int h1 = *(const unsigned short*)(H + (size_t)u1 * 128 + lane * 2);
            int h2 = *(const unsigned short*)(H + (size_t)u2 * 128 + lane * 2);
            int h3 = *(const unsigned short*)(H + (size_t)u3 * 128 + lane * 2);
            f32x2 d0 = __builtin_amdgcn_cvt_pk_f32_fp8(h0, false);
            f32x2 d1 = __builtin_amdgcn_cvt_pk_f32_fp8(h1, false);
            f32x2 d2 = __builtin_amdgcn_cvt_pk_f32_fp8(h2, false);
            f32x2 d3 = __builtin_amdgcn_cvt_pk_f32_fp8(h3, false);
            a0.x += w0 * d0[0]; a0.y += w0 * d0[1];
            a1.x += w1 * d1[0]; a1.y += w1 * d1[1];
            a2.x += w2 * d2[0]; a2.y += w2 * d2[1];
            a3.x += w3 * d3[0]; a3.y += w3 * d3[1];
        }
        for (; j < nj; j++) {
            int u = __shfl(ul, j);
            float w = __shfl(wl, j);
            int hv = *(const unsigned short*)(H + (size_t)u * 128 + lane * 2);
            f32x2 d = __builtin_amdgcn_cvt_pk_f32_fp8(hv, false);
            a0.x += w * d[0]; a0.y += w * d[1];
        }
    }
    float2 acc = make_float2((a0.x + a1.x) + (a2.x + a3.x),
                             (a0.y + a1.y) + (a2.y + a3.y));
    float dv = dinv[v];
    float sl = 2.f * dv * dv;
    int hv = *(const unsigned short*)(H + (size_t)v * 128 + lane * 2);
    f32x2 dsl = __builtin_amdgcn_cvt_pk_f32_fp8(hv, false);
    float2 bb = ((const float2*)bias)[lane];
    float o0 = fmaxf(dv * acc.x + sl * dsl[0] + bb.x, 0.f);
    float o1 = fmaxf(dv * acc.y + sl * dsl[1] + bb.y, 0.f);
    ((uint32*)out)[(size_t)v * 64 + lane] =
        (uint32)f2bf(o0) | ((uint32)f2bf(o1) << 16);
}

__global__ __launch_bounds__(256) void agg_lsm_64(
    const uchar* __restrict__ H, const int* __restrict__ csr,
    const int* __restrict__ rowptr, const int* __restrict__ deg,
    const float* __restrict__ dinv, const float* __restrict__ bias,
    float* __restrict__ out, int n) {
    int v = blockIdx.x * 4 + (threadIdx.x >> 6);
    if (v >= n) return;
    int lane = threadIdx.x & 63;
    int base = rowptr[v], cnt = deg[v];
    float a0 = 0.f, a1 = 0.f, a2 = 0.f, a3 = 0.f;
    for (int j0 = 0; j0 < cnt; j0 += 64) {
        int nj = min(64, cnt - j0);
        int ul = 0; float wl = 0.f;
        if (lane < nj) { ul = csr[base + j0 + lane]; wl = dinv[ul]; }
        int j = 0;
        for (; j + 4 <= nj; j += 4) {
            int u0 = __shfl(ul, j),     u1 = __shfl(ul, j + 1);
            int u2 = __shfl(ul, j + 2), u3 = __shfl(ul, j + 3);
            float w0 = __shfl(wl, j),     w1 = __shfl(wl, j + 1);
            float w2 = __shfl(wl, j + 2), w3 = __shfl(wl, j + 3);
            int h0 = H[(size_t)u0 * 64 + lane];
            int h1 = H[(size_t)u1 * 64 + lane];
            int h2 = H[(size_t)u2 * 64 + lane];
            int h3 = H[(size_t)u3 * 64 + lane];
            a0 += w0 * __builtin_amdgcn_cvt_f32_fp8(h0, 0);
            a1 += w1 * __builtin_amdgcn_cvt_f32_fp8(h1, 0);
            a2 += w2 * __builtin_amdgcn_cvt_f32_fp8(h2, 0);
            a3 += w3 * __builtin_amdgcn_cvt_f32_fp8(h3, 0);
        }
        for (; j < nj; j++) {
            int u = __shfl(ul, j);
            float w = __shfl(wl, j);
            a0 += w * __builtin_amdgcn_cvt_f32_fp8((int)H[(size_t)u * 64 + lane], 0);
        }
    }
    float acc = (a0 + a1) + (a2 + a3);
    float dv = dinv[v];
    float hv = __builtin_amdgcn_cvt_f32_fp8((int)H[(size_t)v * 64 + lane], 0);
    float val = dv * acc + 2.f * dv * dv * hv + bias[lane];
    float m = val;
    for (int o = 32; o > 0; o >>= 1) m = fmaxf(m, __shfl_xor(m, o));
    float e = __expf(val - m);
    float ssum = e;
    for (int o = 32; o > 0; o >>= 1) ssum += __shfl_xor(ssum, o);
    out[(size_t)v * 64 + lane] = val - m - __logf(ssum);
}

// ---------------- launch ----------------

extern "C" void kernel_launch(void* const* d_in, const int* in_sizes, int n_in,
                              void* d_out, int out_size, void* d_ws, size_t ws_size,
                              hipStream_t stream) {
    const float* x  = (const float*)d_in[0];
    const int*   ei = (const int*)d_in[1];
    const float* W1 = (const float*)d_in[2];
    const float* b1 = (const float*)d_in[3];
    const float* W2 = (const float*)d_in[4];
    const float* b2 = (const float*)d_in[5];
    float* out = (float*)d_out;

    const int N = in_sizes[0] / IN_CH;  // 100000
    const int E = in_sizes[1] / 2;      // 1600000
    const int* src = ei;
    const int* dst = ei + E;
    const int NB = (N + 255) >> BSH;    // 391 buckets

    char* w = (char*)d_ws;
    size_t off = 0;
    auto alloc = [&](size_t bytes) -> char* {
        char* p = w + off;
        off = (off + bytes + 255) & ~(size_t)255;
        return p;
    };
    int*   deg    = (int*)alloc((size_t)N * 4);
    int*   rowptr = (int*)alloc((size_t)N * 4);
    int*   bcnt   = (int*)alloc(512 * 4);
    int*   bbase  = (int*)alloc(513 * 4);
    int*   bcur   = (int*)alloc(512 * 4);
    float* dinv   = (float*)alloc((size_t)N * 4);
    int*   csr    = (int*)alloc((size_t)E * 4);
    unsigned short* W1t = (unsigned short*)alloc(128 * 128 * 2);
    unsigned short* W2t = (unsigned short*)alloc(64 * 128 * 2);
    uchar* H1  = (uchar*)alloc((size_t)N * HID_CH);          // fp8, 12.8 MB
    unsigned short* A1b = (unsigned short*)alloc((size_t)N * HID_CH * 2);  // bf16
    uchar* H2  = H1;                     // fp8; H1 dead after agg1
    int2*  pairBuf = (int2*)A1b;         // A1b not written until agg1 (after bucket_build)

    hipMemsetAsync(bcnt, 0, 512 * 4, stream);

    int gP = (E + PB - 1) / PB;         // 391 partition blocks

    wtrans<<<96, 256, 0, stream>>>(W1, W2, W1t, W2t);
    bhist<<<gP, 256, 0, stream>>>(dst, bcnt, E, NB);
    bscan<<<1, 512, 0, stream>>>(bcnt, bbase, bcur, NB, E);
    part1<<<gP, 256, 0, stream>>>(src, dst, bbase, bcur, pairBuf, E, NB);
    bucket_build<<<NB, 256, 0, stream>>>(pairBuf, bbase, rowptr, deg, dinv, csr, N);

    gemm_mfma<128, true><<<(N + 127) / 128, 256, 0, stream>>>(x, W1t, H1, N);
    agg_relu_128<<<(N + 3) / 4, 256, 0, stream>>>(H1, csr, rowptr, deg, dinv, b1, A1b, N);
    gemm_mfma<64, false><<<(N + 127) / 128, 256, 0, stream>>>(A1b, W2t, H2, N);
    agg_lsm_64<<<(N + 3) / 4, 256, 0, stream>>>(H2, csr, rowptr, deg, dinv, b2, out, N);
}

// Round 9
// 261.305 us; speedup vs baseline: 2.4051x; 1.1511x over previous
//
#include <hip/hip_runtime.h>
#include <cstdint>
#include <cstddef>

#define IN_CH 128
#define HID_CH 128
#define OUT_CH 64
#define BSH 8        // nodes per bucket = 256
#define PB 4096      // edges per histogram/partition block

typedef unsigned int uint32;
typedef unsigned char uchar;
typedef short bf16x8 __attribute__((ext_vector_type(8)));
typedef float f32x4 __attribute__((ext_vector_type(4)));
typedef float f32x2 __attribute__((ext_vector_type(2)));

// float -> bf16 round-to-nearest-even
static __device__ __forceinline__ unsigned short f2bf(float f) {
    uint32 u = __float_as_uint(f);
    u += 0x7fffu + ((u >> 16) & 1u);
    return (unsigned short)(u >> 16);
}
// float -> fp8 e4m3 (OCP) single byte via HW cvt
static __device__ __forceinline__ uchar f2fp8(float f) {
    int p = __builtin_amdgcn_cvt_pk_fp8_f32(f, f, 0, false);
    return (uchar)(p & 0xff);
}

// ---------------- CSR build (bucketed, LDS-atomic only) ----------------

__global__ __launch_bounds__(256) void bhist(const int* __restrict__ dst,
                                             int* __restrict__ bcnt, int E, int NB) {
    __shared__ int h[512];
    int t = threadIdx.x;
    int e0 = blockIdx.x * PB;
    int cnt = min(PB, E - e0);
    for (int b = t; b < NB; b += 256) h[b] = 0;
    __syncthreads();
    for (int i = t; i < cnt; i += 256)
        atomicAdd(&h[dst[e0 + i] >> BSH], 1);
    __syncthreads();
    for (int b = t; b < NB; b += 256)
        if (h[b]) atomicAdd(&bcnt[b], h[b]);
}

// cursors start at ZERO (part1 adds bbase[b] itself).
__global__ void bscan(const int* __restrict__ bcnt, int* __restrict__ bbase,
                      int* __restrict__ bcur, int NB, int E) {
    __shared__ int s[512];
    int t = threadIdx.x;
    int v = (t < NB) ? bcnt[t] : 0;
    s[t] = v;
    __syncthreads();
    for (int o = 1; o < 512; o <<= 1) {
        int add = (t >= o) ? s[t - o] : 0;
        __syncthreads();
        s[t] += add;
        __syncthreads();
    }
    if (t < NB) { bbase[t] = s[t] - v; bcur[t] = 0; }
    if (t == 0) bbase[NB] = E;
}

__global__ __launch_bounds__(256) void part1(
    const int* __restrict__ src, const int* __restrict__ dst,
    const int* __restrict__ bbase, int* __restrict__ bcur,
    int2* __restrict__ pairBuf, int E, int NB) {
    __shared__ int hist[512];
    __shared__ int base[512];
    int t = threadIdx.x;
    int e0 = blockIdx.x * PB;
    int cnt = min(PB, E - e0);
    for (int b = t; b < NB; b += 256) hist[b] = 0;
    __syncthreads();
    for (int i = t; i < cnt; i += 256)
        atomicAdd(&hist[dst[e0 + i] >> BSH], 1);
    __syncthreads();
    for (int b = t; b < NB; b += 256) {
        int h = hist[b];
        int gb = (h > 0) ? atomicAdd(&bcur[b], h) : 0;
        base[b] = bbase[b] + gb;
        hist[b] = 0;
    }
    __syncthreads();
    for (int i = t; i < cnt; i += 256) {
        int s = src[e0 + i], d = dst[e0 + i];
        int b = d >> BSH;
        int p = base[b] + atomicAdd(&hist[b], 1);
        pairBuf[p] = make_int2(s, d);
    }
}

__global__ __launch_bounds__(256) void bucket_build(
    const int2* __restrict__ pairBuf, const int* __restrict__ bbase,
    int* __restrict__ rowptr, int* __restrict__ deg, float* __restrict__ dinv,
    int* __restrict__ csr, int N) {
    __shared__ int cnt[256];
    __shared__ int loc[256];
    int b = blockIdx.x, t = threadIdx.x;
    int start = bbase[b], end = bbase[b + 1];
    cnt[t] = 0;
    __syncthreads();
    for (int i = start + t; i < end; i += 256)
        atomicAdd(&cnt[pairBuf[i].y & 255], 1);
    __syncthreads();
    int v = cnt[t];
    loc[t] = v;
    __syncthreads();
    for (int o = 1; o < 256; o <<= 1) {
        int add = (t >= o) ? loc[t - o] : 0;
        __syncthreads();
        loc[t] += add;
        __syncthreads();
    }
    int excl = loc[t] - v;
    int node = (b << BSH) + t;
    if (node < N) {
        rowptr[node] = start + excl;
        deg[node] = v;
        dinv[node] = rsqrtf((float)(v + 2));   // +2 self-loops
    }
    __syncthreads();
    cnt[t] = excl;                              // reuse as cursor
    __syncthreads();
    for (int i = start + t; i < end; i += 256) {
        int2 p = pairBuf[i];
        int q = start + atomicAdd(&cnt[p.y & 255], 1);
        csr[q] = p.x;
    }
}

// ---------------- Weight transpose + bf16 convert (one-shot) ----------------

__global__ void wtrans(const float* __restrict__ W1, const float* __restrict__ W2,
                       unsigned short* __restrict__ W1t, unsigned short* __restrict__ W2t) {
    int t = blockIdx.x * 256 + threadIdx.x;
    if (t < 128 * 128) {
        int nc = t >> 7, k = t & 127;
        W1t[t] = f2bf(W1[k * 128 + nc]);
    }
    int u = t - 128 * 128;
    if (u >= 0 && u < 64 * 128) {
        int nc = u >> 7, k = u & 127;
        W2t[u] = f2bf(W2[k * 64 + nc]);
    }
}

// ---------------- MFMA GEMM: C[n,OUT] = A[n,128] @ W[128,OUT] -> fp8 out ----------

template <int OUT, bool AFP32>
__global__ __launch_bounds__(256) void gemm_mfma(
    const void* __restrict__ Av, const unsigned short* __restrict__ Wt,
    uchar* __restrict__ C, int n) {
    constexpr int AP = 72;    // A chunk pitch (64+8)
    constexpr int WP = 136;   // W pitch (128+8)
    constexpr int NT = OUT / 16;
    __shared__ unsigned short As[128 * AP];
    __shared__ unsigned short Ws[OUT * WP];

    const int t = threadIdx.x;
    const int row0 = blockIdx.x * 128;

    for (int i = t; i < OUT * 16; i += 256) {
        int rr = i >> 4, sq = i & 15;
        *(uint4*)&Ws[rr * WP + sq * 8] = *(const uint4*)(Wt + rr * 128 + sq * 8);
    }

    const int w = t >> 6, l = t & 63;
    const int q = l >> 4, r16 = l & 15;
    const int mbase = w * 32;

    f32x4 acc0[NT], acc1[NT];
    for (int i = 0; i < NT; i++) {
        acc0[i] = (f32x4){0.f, 0.f, 0.f, 0.f};
        acc1[i] = (f32x4){0.f, 0.f, 0.f, 0.f};
    }

    for (int half = 0; half < 2; half++) {
        if (half) __syncthreads();
        if (AFP32) {
            const float* A = (const float*)Av;
            for (int i = t; i < 128 * 16; i += 256) {
                int rr = i >> 4, fq = i & 15;
                float4 v = make_float4(0.f, 0.f, 0.f, 0.f);
                if (row0 + rr < n)
                    v = *(const float4*)(A + (size_t)(row0 + rr) * 128 + half * 64 + fq * 4);
                unsigned short* p = &As[rr * AP + fq * 4];
                p[0] = f2bf(v.x); p[1] = f2bf(v.y); p[2] = f2bf(v.z); p[3] = f2bf(v.w);
            }
        } else {
            const unsigned short* A = (const unsigned short*)Av;
            for (int i = t; i < 128 * 8; i += 256) {
                int rr = i >> 3, sq = i & 7;
                uint4 v = make_uint4(0, 0, 0, 0);
                if (row0 + rr < n)
                    v = *(const uint4*)(A + (size_t)(row0 + rr) * 128 + half * 64 + sq * 8);
                *(uint4*)&As[rr * AP + sq * 8] = v;
            }
        }
        __syncthreads();

#pragma unroll
        for (int kc = 0; kc < 2; kc++) {
            int ko = kc * 32 + q * 8;
            int kow = half * 64 + ko;
            bf16x8 a0 = *(const bf16x8*)&As[(mbase + r16) * AP + ko];
            bf16x8 a1 = *(const bf16x8*)&As[(mbase + 16 + r16) * AP + ko];
#pragma unroll
            for (int nt = 0; nt < NT; nt++) {
                bf16x8 b = *(const bf16x8*)&Ws[(nt * 16 + r16) * WP + kow];
                acc0[nt] = __builtin_amdgcn_mfma_f32_16x16x32_bf16(a0, b, acc0[nt], 0, 0, 0);
                acc1[nt] = __builtin_amdgcn_mfma_f32_16x16x32_bf16(a1, b, acc1[nt], 0, 0, 0);
            }
        }
    }

#pragma unroll
    for (int nt = 0; nt < NT; nt++) {
#pragma unroll
        for (int p = 0; p < 4; p++) {
            int rr = row0 + mbase + q * 4 + p;
            if (rr < n) C[(size_t)rr * OUT + nt * 16 + r16] = f2fp8(acc0[nt][p]);
            if (rr + 16 < n) C[(size_t)(rr + 16) * OUT + nt * 16 + r16] = f2fp8(acc1[nt][p]);
        }
    }
}

// ---------------- Aggregation: HALF-WAVE per node -------------------------------
// 32 lanes own one node; a full wave streams 2 nodes' edges in one instruction
// stream (2 edges per issue slot). Broadcasts stay in-half: __shfl(x, j|(lane&32)).

// agg1: 128 ch, lane covers 4 ch (uint = 4 fp8). out = bf16.
__global__ __launch_bounds__(256) void agg_relu_128(
    const uchar* __restrict__ H, const int* __restrict__ csr,
    const int* __restrict__ rowptr, const int* __restrict__ deg,
    const float* __restrict__ dinv, const float* __restrict__ bias,
    unsigned short* __restrict__ out, int n) {
    int v = blockIdx.x * 8 + (threadIdx.x >> 5);
    int hl = threadIdx.x & 31;
    int half32 = threadIdx.x & 32;
    bool valid = v < n;
    int vc = valid ? v : 0;
    int base = rowptr[vc];
    int cnt = valid ? deg[vc] : 0;
    int cntO = __shfl(cnt, (int)(threadIdx.x & 63) ^ 32);
    int cntmax = max(cnt, cntO);

    float4 a0 = make_float4(0.f, 0.f, 0.f, 0.f), a1 = a0, a2 = a0, a3 = a0;
    for (int j0 = 0; j0 < cntmax; j0 += 32) {
        int nj = min(32, cnt - j0);            // may be <= 0 for the lighter half
        int ul = 0; float wl = 0.f;
        if (hl < nj) { ul = csr[base + j0 + hl]; wl = dinv[ul]; }
        int njmax = min(32, cntmax - j0);
        int j = 0;
        for (; j + 4 <= njmax; j += 4) {
            int s0 = j | half32, s1 = (j + 1) | half32,
                s2 = (j + 2) | half32, s3 = (j + 3) | half32;
            int u0 = __shfl(ul, s0), u1 = __shfl(ul, s1);
            int u2 = __shfl(ul, s2), u3 = __shfl(ul, s3);
            float w0 = __shfl(wl, s0), w1 = __shfl(wl, s1);
            float w2 = __shfl(wl, s2), w3 = __shfl(wl, s3);
            uint32 h0 = *(const uint32*)(H + (size_t)u0 * 128 + hl * 4);
            uint32 h1 = *(const uint32*)(H + (size_t)u1 * 128 + hl * 4);
            uint32 h2 = *(const uint32*)(H + (size_t)u2 * 128 + hl * 4);
            uint32 h3 = *(const uint32*)(H + (size_t)u3 * 128 + hl * 4);
            f32x2 l0 = __builtin_amdgcn_cvt_pk_f32_fp8(h0, false);
            f32x2 g0 = __builtin_amdgcn_cvt_pk_f32_fp8(h0, true);
            f32x2 l1 = __builtin_amdgcn_cvt_pk_f32_fp8(h1, false);
            f32x2 g1 = __builtin_amdgcn_cvt_pk_f32_fp8(h1, true);
            f32x2 l2 = __builtin_amdgcn_cvt_pk_f32_fp8(h2, false);
            f32x2 g2 = __builtin_amdgcn_cvt_pk_f32_fp8(h2, true);
            f32x2 l3 = __builtin_amdgcn_cvt_pk_f32_fp8(h3, false);
            f32x2 g3 = __builtin_amdgcn_cvt_pk_f32_fp8(h3, true);
            a0.x += w0 * l0[0]; a0.y += w0 * l0[1]; a0.z += w0 * g0[0]; a0.w += w0 * g0[1];
            a1.x += w1 * l1[0]; a1.y += w1 * l1[1]; a1.z += w1 * g1[0]; a1.w += w1 * g1[1];
            a2.x += w2 * l2[0]; a2.y += w2 * l2[1]; a2.z += w2 * g2[0]; a2.w += w2 * g2[1];
            a3.x += w3 * l3[0]; a3.y += w3 * l3[1]; a3.z += w3 * g3[0]; a3.w += w3 * g3[1];
        }
        for (; j < njmax; j++) {
            int s = j | half32;
            int u = __shfl(ul, s);
            float wv = __shfl(wl, s);
            uint32 h = *(const uint32*)(H + (size_t)u * 128 + hl * 4);
            f32x2 lo = __builtin_amdgcn_cvt_pk_f32_fp8(h, false);
            f32x2 gg = __builtin_amdgcn_cvt_pk_f32_fp8(h, true);
            a0.x += wv * lo[0]; a0.y += wv * lo[1]; a0.z += wv * gg[0]; a0.w += wv * gg[1];
        }
    }
    float4 acc = make_float4((a0.x + a1.x) + (a2.x + a3.x),
                             (a0.y + a1.y) + (a2.y + a3.y),
                             (a0.z + a1.z) + (a2.z + a3.z),
                             (a0.w + a1.w) + (a2.w + a3.w));
    if (valid) {
        float dv = dinv[vc];
        float sl = 2.f * dv * dv;
        uint32 hv = *(const uint32*)(H + (size_t)vc * 128 + hl * 4);
        f32x2 slo = __builtin_amdgcn_cvt_pk_f32_fp8(hv, false);
        f32x2 shi = __builtin_amdgcn_cvt_pk_f32_fp8(hv, true);
        float4 bb = ((const float4*)bias)[hl];
        float o0 = fmaxf(dv * acc.x + sl * slo[0] + bb.x, 0.f);
        float o1 = fmaxf(dv * acc.y + sl * slo[1] + bb.y, 0.f);
        float o2 = fmaxf(dv * acc.z + sl * shi[0] + bb.z, 0.f);
        float o3 = fmaxf(dv * acc.w + sl * shi[1] + bb.w, 0.f);
        uint2 pk;
        pk.x = (uint32)f2bf(o0) | ((uint32)f2bf(o1) << 16);
        pk.y = (uint32)f2bf(o2) | ((uint32)f2bf(o3) << 16);
        *(uint2*)(out + (size_t)vc * 128 + hl * 4) = pk;
    }
}

// agg2: 64 ch, lane covers 2 ch (ushort = 2 fp8). log_softmax in-half.
__global__ __launch_bounds__(256) void agg_lsm_64(
    const uchar* __restrict__ H, const int* __restrict__ csr,
    const int* __restrict__ rowptr, const int* __restrict__ deg,
    const float* __restrict__ dinv, const float* __restrict__ bias,
    float* __restrict__ out, int n) {
    int v = blockIdx.x * 8 + (threadIdx.x >> 5);
    int hl = threadIdx.x & 31;
    int half32 = threadIdx.x & 32;
    bool valid = v < n;
    int vc = valid ? v : 0;
    int base = rowptr[vc];
    int cnt = valid ? deg[vc] : 0;
    int cntO = __shfl(cnt, (int)(threadIdx.x & 63) ^ 32);
    int cntmax = max(cnt, cntO);

    float2 a0 = make_float2(0.f, 0.f), a1 = a0, a2 = a0, a3 = a0;
    for (int j0 = 0; j0 < cntmax; j0 += 32) {
        int nj = min(32, cnt - j0);
        int ul = 0; float wl = 0.f;
        if (hl < nj) { ul = csr[base + j0 + hl]; wl = dinv[ul]; }
        int njmax = min(32, cntmax - j0);
        int j = 0;
        for (; j + 4 <= njmax; j += 4) {
            int s0 = j | half32, s1 = (j + 1) | half32,
                s2 = (j + 2) | half32, s3 = (j + 3) | half32;
            int u0 = __shfl(ul, s0), u1 = __shfl(ul, s1);
            int u2 = __shfl(ul, s2), u3 = __shfl(ul, s3);
            float w0 = __shfl(wl, s0), w1 = __shfl(wl, s1);
            float w2 = __shfl(wl, s2), w3 = __shfl(wl, s3);
            int h0 = *(const unsigned short*)(H + (size_t)u0 * 64 + hl * 2);
            int h1 = *(const unsigned short*)(H + (size_t)u1 * 64 + hl * 2);
            int h2 = *(const unsigned short*)(H + (size_t)u2 * 64 + hl * 2);
            int h3 = *(const unsigned short*)(H + (size_t)u3 * 64 + hl * 2);
            f32x2 d0 = __builtin_amdgcn_cvt_pk_f32_fp8(h0, false);
            f32x2 d1 = __builtin_amdgcn_cvt_pk_f32_fp8(h1, false);
            f32x2 d2 = __builtin_amdgcn_cvt_pk_f32_fp8(h2, false);
            f32x2 d3 = __builtin_amdgcn_cvt_pk_f32_fp8(h3, false);
            a0.x += w0 * d0[0]; a0.y += w0 * d0[1];
            a1.x += w1 * d1[0]; a1.y += w1 * d1[1];
            a2.x += w2 * d2[0]; a2.y += w2 * d2[1];
            a3.x += w3 * d3[0]; a3.y += w3 * d3[1];
        }
        for (; j < njmax; j++) {
            int s = j | half32;
            int u = __shfl(ul, s);
            float wv = __shfl(wl, s);
            int h = *(const unsigned short*)(H + (size_t)u * 64 + hl * 2);
            f32x2 d = __builtin_amdgcn_cvt_pk_f32_fp8(h, false);
            a0.x += wv * d[0]; a0.y += wv * d[1];
        }
    }
    float2 acc = make_float2((a0.x + a1.x) + (a2.x + a3.x),
                             (a0.y + a1.y) + (a2.y + a3.y));
    float dv = dinv[vc];
    int hv = *(const unsigned short*)(H + (size_t)vc * 64 + hl * 2);
    f32x2 ds = __builtin_amdgcn_cvt_pk_f32_fp8(hv, false);
    float2 bb = ((const float2*)bias)[hl];
    float sl = 2.f * dv * dv;
    float v0 = dv * acc.x + sl * ds[0] + bb.x;
    float v1 = dv * acc.y + sl * ds[1] + bb.y;
    // log_softmax across the 64 channels held by this 32-lane half
    float m = fmaxf(v0, v1);
    for (int o = 16; o > 0; o >>= 1) m = fmaxf(m, __shfl_xor(m, o));
    float e = __expf(v0 - m) + __expf(v1 - m);
    for (int o = 16; o > 0; o >>= 1) e += __shfl_xor(e, o);
    float ls = m + __logf(e);
    if (valid)
        *(float2*)(out + (size_t)vc * 64 + hl * 2) = make_float2(v0 - ls, v1 - ls);
}

// ---------------- launch ----------------

extern "C" void kernel_launch(void* const* d_in, const int* in_sizes, int n_in,
                              void* d_out, int out_size, void* d_ws, size_t ws_size,
                              hipStream_t stream) {
    const float* x  = (const float*)d_in[0];
    const int*   ei = (const int*)d_in[1];
    const float* W1 = (const float*)d_in[2];
    const float* b1 = (const float*)d_in[3];
    const float* W2 = (const float*)d_in[4];
    const float* b2 = (const float*)d_in[5];
    float* out = (float*)d_out;

    const int N = in_sizes[0] / IN_CH;  // 100000
    const int E = in_sizes[1] / 2;      // 1600000
    const int* src = ei;
    const int* dst = ei + E;
    const int NB = (N + 255) >> BSH;    // 391 buckets

    char* w = (char*)d_ws;
    size_t off = 0;
    auto alloc = [&](size_t bytes) -> char* {
        char* p = w + off;
        off = (off + bytes + 255) & ~(size_t)255;
        return p;
    };
    int*   deg    = (int*)alloc((size_t)N * 4);
    int*   rowptr = (int*)alloc((size_t)N * 4);
    int*   bcnt   = (int*)alloc(512 * 4);
    int*   bbase  = (int*)alloc(513 * 4);
    int*   bcur   = (int*)alloc(512 * 4);
    float* dinv   = (float*)alloc((size_t)N * 4);
    int*   csr    = (int*)alloc((size_t)E * 4);
    unsigned short* W1t = (unsigned short*)alloc(128 * 128 * 2);
    unsigned short* W2t = (unsigned short*)alloc(64 * 128 * 2);
    uchar* H1  = (uchar*)alloc((size_t)N * HID_CH);          // fp8, 12.8 MB
    unsigned short* A1b = (unsigned short*)alloc((size_t)N * HID_CH * 2);  // bf16
    uchar* H2  = H1;                     // fp8; H1 dead after agg1
    int2*  pairBuf = (int2*)A1b;         // A1b not written until agg1 (after bucket_build)

    hipMemsetAsync(bcnt, 0, 512 * 4, stream);

    int gP = (E + PB - 1) / PB;         // 391 partition blocks

    wtrans<<<96, 256, 0, stream>>>(W1, W2, W1t, W2t);
    bhist<<<gP, 256, 0, stream>>>(dst, bcnt, E, NB);
    bscan<<<1, 512, 0, stream>>>(bcnt, bbase, bcur, NB, E);
    part1<<<gP, 256, 0, stream>>>(src, dst, bbase, bcur, pairBuf, E, NB);
    bucket_build<<<NB, 256, 0, stream>>>(pairBuf, bbase, rowptr, deg, dinv, csr, N);

    gemm_mfma<128, true><<<(N + 127) / 128, 256, 0, stream>>>(x, W1t, H1, N);
    agg_relu_128<<<(N + 7) / 8, 256, 0, stream>>>(H1, csr, rowptr, deg, dinv, b1, A1b, N);
    gemm_mfma<64, false><<<(N + 127) / 128, 256, 0, stream>>>(A1b, W2t, H2, N);
    agg_lsm_64<<<(N + 7) / 8, 256, 0, stream>>>(H2, csr, rowptr, deg, dinv, b2, out, N);
}

// Round 10
// 252.882 us; speedup vs baseline: 2.4852x; 1.0333x over previous
//
#include <hip/hip_runtime.h>
#include <cstdint>
#include <cstddef>

#define IN_CH 128
#define HID_CH 128
#define OUT_CH 64
#define BSH 8        // nodes per bucket = 256
#define PB 4096      // edges per histogram/partition block

typedef unsigned int uint32;
typedef unsigned char uchar;
typedef short bf16x8 __attribute__((ext_vector_type(8)));
typedef float f32x4 __attribute__((ext_vector_type(4)));
typedef float f32x2 __attribute__((ext_vector_type(2)));

// float -> bf16 round-to-nearest-even
static __device__ __forceinline__ unsigned short f2bf(float f) {
    uint32 u = __float_as_uint(f);
    u += 0x7fffu + ((u >> 16) & 1u);
    return (unsigned short)(u >> 16);
}
// float -> fp8 e4m3 (OCP) single byte via HW cvt
static __device__ __forceinline__ uchar f2fp8(float f) {
    int p = __builtin_amdgcn_cvt_pk_fp8_f32(f, f, 0, false);
    return (uchar)(p & 0xff);
}

// ---------------- CSR build (bucketed, LDS-atomic only) ----------------

// bhist over buckets; wtrans fused into trailing blocks (independent work).
__global__ __launch_bounds__(256) void bhist_wtrans(
    const int* __restrict__ dst, int* __restrict__ bcnt, int E, int NB, int gP,
    const float* __restrict__ W1, const float* __restrict__ W2,
    unsigned short* __restrict__ W1t, unsigned short* __restrict__ W2t) {
    if (blockIdx.x >= (uint32)gP) {
        int t = (blockIdx.x - gP) * 256 + threadIdx.x;
        if (t < 128 * 128) {
            int nc = t >> 7, k = t & 127;
            W1t[t] = f2bf(W1[k * 128 + nc]);
        }
        int u = t - 128 * 128;
        if (u >= 0 && u < 64 * 128) {
            int nc = u >> 7, k = u & 127;
            W2t[u] = f2bf(W2[k * 64 + nc]);
        }
        return;
    }
    __shared__ int h[512];
    int t = threadIdx.x;
    int e0 = blockIdx.x * PB;
    int cnt = min(PB, E - e0);
    for (int b = t; b < NB; b += 256) h[b] = 0;
    __syncthreads();
    for (int i = t; i < cnt; i += 256)
        atomicAdd(&h[dst[e0 + i] >> BSH], 1);
    __syncthreads();
    for (int b = t; b < NB; b += 256)
        if (h[b]) atomicAdd(&bcnt[b], h[b]);
}

// cursors start at ZERO (part1 adds bbase[b] itself).
__global__ void bscan(const int* __restrict__ bcnt, int* __restrict__ bbase,
                      int* __restrict__ bcur, int NB, int E) {
    __shared__ int s[512];
    int t = threadIdx.x;
    int v = (t < NB) ? bcnt[t] : 0;
    s[t] = v;
    __syncthreads();
    for (int o = 1; o < 512; o <<= 1) {
        int add = (t >= o) ? s[t - o] : 0;
        __syncthreads();
        s[t] += add;
        __syncthreads();
    }
    if (t < NB) { bbase[t] = s[t] - v; bcur[t] = 0; }
    if (t == 0) bbase[NB] = E;
}

// part1: edges cached in LDS (single global read), histogram, then grouped write.
__global__ __launch_bounds__(256) void part1(
    const int* __restrict__ src, const int* __restrict__ dst,
    const int* __restrict__ bbase, int* __restrict__ bcur,
    int2* __restrict__ pairBuf, int E, int NB) {
    __shared__ int2 pairs[PB];          // 32 KB
    __shared__ int hist[512];
    __shared__ int base[512];
    int t = threadIdx.x;
    int e0 = blockIdx.x * PB;
    int cnt = min(PB, E - e0);
    for (int b = t; b < NB; b += 256) hist[b] = 0;
    __syncthreads();
    for (int i = t; i < cnt; i += 256) {
        int s = src[e0 + i], d = dst[e0 + i];
        pairs[i] = make_int2(s, d);
        atomicAdd(&hist[d >> BSH], 1);
    }
    __syncthreads();
    for (int b = t; b < NB; b += 256) {
        int h = hist[b];
        int gb = (h > 0) ? atomicAdd(&bcur[b], h) : 0;
        base[b] = bbase[b] + gb;
        hist[b] = 0;
    }
    __syncthreads();
    for (int i = t; i < cnt; i += 256) {
        int2 p = pairs[i];
        int b = p.y >> BSH;
        int q = base[b] + atomicAdd(&hist[b], 1);
        pairBuf[q] = p;
    }
}

__global__ __launch_bounds__(256) void bucket_build(
    const int2* __restrict__ pairBuf, const int* __restrict__ bbase,
    int* __restrict__ rowptr, int* __restrict__ deg, float* __restrict__ dinv,
    int* __restrict__ csr, int N) {
    __shared__ int cnt[256];
    __shared__ int loc[256];
    int b = blockIdx.x, t = threadIdx.x;
    int start = bbase[b], end = bbase[b + 1];
    cnt[t] = 0;
    __syncthreads();
    for (int i = start + t; i < end; i += 256)
        atomicAdd(&cnt[pairBuf[i].y & 255], 1);
    __syncthreads();
    int v = cnt[t];
    loc[t] = v;
    __syncthreads();
    for (int o = 1; o < 256; o <<= 1) {
        int add = (t >= o) ? loc[t - o] : 0;
        __syncthreads();
        loc[t] += add;
        __syncthreads();
    }
    int excl = loc[t] - v;
    int node = (b << BSH) + t;
    if (node < N) {
        rowptr[node] = start + excl;
        deg[node] = v;
        dinv[node] = rsqrtf((float)(v + 2));   // +2 self-loops
    }
    __syncthreads();
    cnt[t] = excl;                              // reuse as cursor
    __syncthreads();
    for (int i = start + t; i < end; i += 256) {
        int2 p = pairBuf[i];
        int q = start + atomicAdd(&cnt[p.y & 255], 1);
        csr[q] = p.x;
    }
}

// ---------------- MFMA GEMM: C[n,OUT] = A[n,128] @ W[128,OUT] -> fp8 out ----------

template <int OUT, bool AFP32>
__global__ __launch_bounds__(256) void gemm_mfma(
    const void* __restrict__ Av, const unsigned short* __restrict__ Wt,
    uchar* __restrict__ C, int n) {
    constexpr int AP = 72;    // A chunk pitch (64+8)
    constexpr int WP = 136;   // W pitch (128+8)
    constexpr int NT = OUT / 16;
    __shared__ unsigned short As[128 * AP];
    __shared__ unsigned short Ws[OUT * WP];

    const int t = threadIdx.x;
    const int row0 = blockIdx.x * 128;

    for (int i = t; i < OUT * 16; i += 256) {
        int rr = i >> 4, sq = i & 15;
        *(uint4*)&Ws[rr * WP + sq * 8] = *(const uint4*)(Wt + rr * 128 + sq * 8);
    }

    const int w = t >> 6, l = t & 63;
    const int q = l >> 4, r16 = l & 15;
    const int mbase = w * 32;

    f32x4 acc0[NT], acc1[NT];
    for (int i = 0; i < NT; i++) {
        acc0[i] = (f32x4){0.f, 0.f, 0.f, 0.f};
        acc1[i] = (f32x4){0.f, 0.f, 0.f, 0.f};
    }

    for (int half = 0; half < 2; half++) {
        if (half) __syncthreads();
        if (AFP32) {
            const float* A = (const float*)Av;
            for (int i = t; i < 128 * 16; i += 256) {
                int rr = i >> 4, fq = i & 15;
                float4 v = make_float4(0.f, 0.f, 0.f, 0.f);
                if (row0 + rr < n)
                    v = *(const float4*)(A + (size_t)(row0 + rr) * 128 + half * 64 + fq * 4);
                unsigned short* p = &As[rr * AP + fq * 4];
                p[0] = f2bf(v.x); p[1] = f2bf(v.y); p[2] = f2bf(v.z); p[3] = f2bf(v.w);
            }
        } else {
            const unsigned short* A = (const unsigned short*)Av;
            for (int i = t; i < 128 * 8; i += 256) {
                int rr = i >> 3, sq = i & 7;
                uint4 v = make_uint4(0, 0, 0, 0);
                if (row0 + rr < n)
                    v = *(const uint4*)(A + (size_t)(row0 + rr) * 128 + half * 64 + sq * 8);
                *(uint4*)&As[rr * AP + sq * 8] = v;
            }
        }
        __syncthreads();

#pragma unroll
        for (int kc = 0; kc < 2; kc++) {
            int ko = kc * 32 + q * 8;
            int kow = half * 64 + ko;
            bf16x8 a0 = *(const bf16x8*)&As[(mbase + r16) * AP + ko];
            bf16x8 a1 = *(const bf16x8*)&As[(mbase + 16 + r16) * AP + ko];
#pragma unroll
            for (int nt = 0; nt < NT; nt++) {
                bf16x8 b = *(const bf16x8*)&Ws[(nt * 16 + r16) * WP + kow];
                acc0[nt] = __builtin_amdgcn_mfma_f32_16x16x32_bf16(a0, b, acc0[nt], 0, 0, 0);
                acc1[nt] = __builtin_amdgcn_mfma_f32_16x16x32_bf16(a1, b, acc1[nt], 0, 0, 0);
            }
        }
    }

#pragma unroll
    for (int nt = 0; nt < NT; nt++) {
#pragma unroll
        for (int p = 0; p < 4; p++) {
            int rr = row0 + mbase + q * 4 + p;
            if (rr < n) C[(size_t)rr * OUT + nt * 16 + r16] = f2fp8(acc0[nt][p]);
            if (rr + 16 < n) C[(size_t)(rr + 16) * OUT + nt * 16 + r16] = f2fp8(acc1[nt][p]);
        }
    }
}

// ---------------- Aggregation: QUARTER-WAVE per node ----------------------------
// 16 lanes own one node; a full wave streams 4 nodes (4 edges per issue slot),
// unroll-4 -> 16 edge-gathers in flight per wave. Broadcast: __shfl(x, j|(lane&48)).
// Per-group-uniform trip counts; exec-mask divergence handles degree imbalance.

// agg1: 128 ch, lane covers 8 ch (uint2 = 8 fp8). out = bf16.
__global__ __launch_bounds__(256) void agg_relu_128(
    const uchar* __restrict__ H, const int* __restrict__ csr,
    const int* __restrict__ rowptr, const int* __restrict__ deg,
    const float* __restrict__ dinv, const float* __restrict__ bias,
    unsigned short* __restrict__ out, int n) {
    int v = blockIdx.x * 16 + (threadIdx.x >> 4);
    int hl = threadIdx.x & 15;
    int gsel = threadIdx.x & 48;
    bool valid = v < n;
    int vc = valid ? v : 0;
    int base = rowptr[vc];
    int cnt = valid ? deg[vc] : 0;

    float4 aL0 = make_float4(0.f, 0.f, 0.f, 0.f), aH0 = aL0;
    float4 aL1 = aL0, aH1 = aL0, aL2 = aL0, aH2 = aL0, aL3 = aL0, aH3 = aL0;

    for (int j0 = 0; j0 < cnt; j0 += 16) {
        int nj = min(16, cnt - j0);
        int ul = 0; float wl = 0.f;
        if (hl < nj) { ul = csr[base + j0 + hl]; wl = dinv[ul]; }
        int j = 0;
        for (; j + 4 <= nj; j += 4) {
            int s0 = j | gsel, s1 = (j + 1) | gsel, s2 = (j + 2) | gsel, s3 = (j + 3) | gsel;
            int u0 = __shfl(ul, s0), u1 = __shfl(ul, s1);
            int u2 = __shfl(ul, s2), u3 = __shfl(ul, s3);
            float w0 = __shfl(wl, s0), w1 = __shfl(wl, s1);
            float w2 = __shfl(wl, s2), w3 = __shfl(wl, s3);
            uint2 h0 = *(const uint2*)(H + (size_t)u0 * 128 + hl * 8);
            uint2 h1 = *(const uint2*)(H + (size_t)u1 * 128 + hl * 8);
            uint2 h2 = *(const uint2*)(H + (size_t)u2 * 128 + hl * 8);
            uint2 h3 = *(const uint2*)(H + (size_t)u3 * 128 + hl * 8);
            {
                f32x2 p0 = __builtin_amdgcn_cvt_pk_f32_fp8(h0.x, false);
                f32x2 p1 = __builtin_amdgcn_cvt_pk_f32_fp8(h0.x, true);
                f32x2 p2 = __builtin_amdgcn_cvt_pk_f32_fp8(h0.y, false);
                f32x2 p3 = __builtin_amdgcn_cvt_pk_f32_fp8(h0.y, true);
                aL0.x += w0 * p0[0]; aL0.y += w0 * p0[1]; aL0.z += w0 * p1[0]; aL0.w += w0 * p1[1];
                aH0.x += w0 * p2[0]; aH0.y += w0 * p2[1]; aH0.z += w0 * p3[0]; aH0.w += w0 * p3[1];
            }
            {
                f32x2 p0 = __builtin_amdgcn_cvt_pk_f32_fp8(h1.x, false);
                f32x2 p1 = __builtin_amdgcn_cvt_pk_f32_fp8(h1.x, true);
                f32x2 p2 = __builtin_amdgcn_cvt_pk_f32_fp8(h1.y, false);
                f32x2 p3 = __builtin_amdgcn_cvt_pk_f32_fp8(h1.y, true);
                aL1.x += w1 * p0[0]; aL1.y += w1 * p0[1]; aL1.z += w1 * p1[0]; aL1.w += w1 * p1[1];
                aH1.x += w1 * p2[0]; aH1.y += w1 * p2[1]; aH1.z += w1 * p3[0]; aH1.w += w1 * p3[1];
            }
            {
                f32x2 p0 = __builtin_amdgcn_cvt_pk_f32_fp8(h2.x, false);
                f32x2 p1 = __builtin_amdgcn_cvt_pk_f32_fp8(h2.x, true);
                f32x2 p2 = __builtin_amdgcn_cvt_pk_f32_fp8(h2.y, false);
                f32x2 p3 = __builtin_amdgcn_cvt_pk_f32_fp8(h2.y, true);
                aL2.x += w2 * p0[0]; aL2.y += w2 * p0[1]; aL2.z += w2 * p1[0]; aL2.w += w2 * p1[1];
                aH2.x += w2 * p2[0]; aH2.y += w2 * p2[1]; aH2.z += w2 * p3[0]; aH2.w += w2 * p3[1];
            }
            {
                f32x2 p0 = __builtin_amdgcn_cvt_pk_f32_fp8(h3.x, false);
                f32x2 p1 = __builtin_amdgcn_cvt_pk_f32_fp8(h3.x, true);
                f32x2 p2 = __builtin_amdgcn_cvt_pk_f32_fp8(h3.y, false);
                f32x2 p3 = __builtin_amdgcn_cvt_pk_f32_fp8(h3.y, true);
                aL3.x += w3 * p0[0]; aL3.y += w3 * p0[1]; aL3.z += w3 * p1[0]; aL3.w += w3 * p1[1];
                aH3.x += w3 * p2[0]; aH3.y += w3 * p2[1]; aH3.z += w3 * p3[0]; aH3.w += w3 * p3[1];
            }
        }
        for (; j < nj; j++) {
            int s = j | gsel;
            int u = __shfl(ul, s);
            float wv = __shfl(wl, s);
            uint2 h = *(const uint2*)(H + (size_t)u * 128 + hl * 8);
            f32x2 p0 = __builtin_amdgcn_cvt_pk_f32_fp8(h.x, false);
            f32x2 p1 = __builtin_amdgcn_cvt_pk_f32_fp8(h.x, true);
            f32x2 p2 = __builtin_amdgcn_cvt_pk_f32_fp8(h.y, false);
            f32x2 p3 = __builtin_amdgcn_cvt_pk_f32_fp8(h.y, true);
            aL0.x += wv * p0[0]; aL0.y += wv * p0[1]; aL0.z += wv * p1[0]; aL0.w += wv * p1[1];
            aH0.x += wv * p2[0]; aH0.y += wv * p2[1]; aH0.z += wv * p3[0]; aH0.w += wv * p3[1];
        }
    }
    if (valid) {
        float4 aL = make_float4((aL0.x + aL1.x) + (aL2.x + aL3.x),
                                (aL0.y + aL1.y) + (aL2.y + aL3.y),
                                (aL0.z + aL1.z) + (aL2.z + aL3.z),
                                (aL0.w + aL1.w) + (aL2.w + aL3.w));
        float4 aH = make_float4((aH0.x + aH1.x) + (aH2.x + aH3.x),
                                (aH0.y + aH1.y) + (aH2.y + aH3.y),
                                (aH0.z + aH1.z) + (aH2.z + aH3.z),
                                (aH0.w + aH1.w) + (aH2.w + aH3.w));
        float dv = dinv[vc];
        float sl = 2.f * dv * dv;
        uint2 hv = *(const uint2*)(H + (size_t)vc * 128 + hl * 8);
        f32x2 s0 = __builtin_amdgcn_cvt_pk_f32_fp8(hv.x, false);
        f32x2 s1 = __builtin_amdgcn_cvt_pk_f32_fp8(hv.x, true);
        f32x2 s2 = __builtin_amdgcn_cvt_pk_f32_fp8(hv.y, false);
        f32x2 s3 = __builtin_amdgcn_cvt_pk_f32_fp8(hv.y, true);
        const float4* bp = (const float4*)(bias + hl * 8);
        float4 b0 = bp[0], b1 = bp[1];
        float o0 = fmaxf(dv * aL.x + sl * s0[0] + b0.x, 0.f);
        float o1 = fmaxf(dv * aL.y + sl * s0[1] + b0.y, 0.f);
        float o2 = fmaxf(dv * aL.z + sl * s1[0] + b0.z, 0.f);
        float o3 = fmaxf(dv * aL.w + sl * s1[1] + b0.w, 0.f);
        float o4 = fmaxf(dv * aH.x + sl * s2[0] + b1.x, 0.f);
        float o5 = fmaxf(dv * aH.y + sl * s2[1] + b1.y, 0.f);
        float o6 = fmaxf(dv * aH.z + sl * s3[0] + b1.z, 0.f);
        float o7 = fmaxf(dv * aH.w + sl * s3[1] + b1.w, 0.f);
        uint4 pk;
        pk.x = (uint32)f2bf(o0) | ((uint32)f2bf(o1) << 16);
        pk.y = (uint32)f2bf(o2) | ((uint32)f2bf(o3) << 16);
        pk.z = (uint32)f2bf(o4) | ((uint32)f2bf(o5) << 16);
        pk.w = (uint32)f2bf(o6) | ((uint32)f2bf(o7) << 16);
        *(uint4*)(out + (size_t)vc * 128 + hl * 8) = pk;
    }
}

// agg2: 64 ch, lane covers 4 ch (uint = 4 fp8). log_softmax within group of 16.
__global__ __launch_bounds__(256) void agg_lsm_64(
    const uchar* __restrict__ H, const int* __restrict__ csr,
    const int* __restrict__ rowptr, const int* __restrict__ deg,
    const float* __restrict__ dinv, const float* __restrict__ bias,
    float* __restrict__ out, int n) {
    int v = blockIdx.x * 16 + (threadIdx.x >> 4);
    int hl = threadIdx.x & 15;
    int gsel = threadIdx.x & 48;
    bool valid = v < n;
    int vc = valid ? v : 0;
    int base = rowptr[vc];
    int cnt = valid ? deg[vc] : 0;

    float4 a0 = make_float4(0.f, 0.f, 0.f, 0.f), a1 = a0, a2 = a0, a3 = a0;
    for (int j0 = 0; j0 < cnt; j0 += 16) {
        int nj = min(16, cnt - j0);
        int ul = 0; float wl = 0.f;
        if (hl < nj) { ul = csr[base + j0 + hl]; wl = dinv[ul]; }
        int j = 0;
        for (; j + 4 <= nj; j += 4) {
            int s0 = j | gsel, s1 = (j + 1) | gsel, s2 = (j + 2) | gsel, s3 = (j + 3) | gsel;
            int u0 = __shfl(ul, s0), u1 = __shfl(ul, s1);
            int u2 = __shfl(ul, s2), u3 = __shfl(ul, s3);
            float w0 = __shfl(wl, s0), w1 = __shfl(wl, s1);
            float w2 = __shfl(wl, s2), w3 = __shfl(wl, s3);
            uint32 h0 = *(const uint32*)(H + (size_t)u0 * 64 + hl * 4);
            uint32 h1 = *(const uint32*)(H + (size_t)u1 * 64 + hl * 4);
            uint32 h2 = *(const uint32*)(H + (size_t)u2 * 64 + hl * 4);
            uint32 h3 = *(const uint32*)(H + (size_t)u3 * 64 + hl * 4);
            f32x2 l0 = __builtin_amdgcn_cvt_pk_f32_fp8(h0, false);
            f32x2 g0 = __builtin_amdgcn_cvt_pk_f32_fp8(h0, true);
            f32x2 l1 = __builtin_amdgcn_cvt_pk_f32_fp8(h1, false);
            f32x2 g1 = __builtin_amdgcn_cvt_pk_f32_fp8(h1, true);
            f32x2 l2 = __builtin_amdgcn_cvt_pk_f32_fp8(h2, false);
            f32x2 g2 = __builtin_amdgcn_cvt_pk_f32_fp8(h2, true);
            f32x2 l3 = __builtin_amdgcn_cvt_pk_f32_fp8(h3, false);
            f32x2 g3 = __builtin_amdgcn_cvt_pk_f32_fp8(h3, true);
            a0.x += w0 * l0[0]; a0.y += w0 * l0[1]; a0.z += w0 * g0[0]; a0.w += w0 * g0[1];
            a1.x += w1 * l1[0]; a1.y += w1 * l1[1]; a1.z += w1 * g1[0]; a1.w += w1 * g1[1];
            a2.x += w2 * l2[0]; a2.y += w2 * l2[1]; a2.z += w2 * g2[0]; a2.w += w2 * g2[1];
            a3.x += w3 * l3[0]; a3.y += w3 * l3[1]; a3.z += w3 * g3[0]; a3.w += w3 * g3[1];
        }
        for (; j < nj; j++) {
            int s = j | gsel;
            int u = __shfl(ul, s);
            float wv = __shfl(wl, s);
            uint32 h = *(const uint32*)(H + (size_t)u * 64 + hl * 4);
            f32x2 lo = __builtin_amdgcn_cvt_pk_f32_fp8(h, false);
            f32x2 gg = __builtin_amdgcn_cvt_pk_f32_fp8(h, true);
            a0.x += wv * lo[0]; a0.y += wv * lo[1]; a0.z += wv * gg[0]; a0.w += wv * gg[1];
        }
    }
    float4 acc = make_float4((a0.x + a1.x) + (a2.x + a3.x),
                             (a0.y + a1.y) + (a2.y + a3.y),
                             (a0.z + a1.z) + (a2.z + a3.z),
                             (a0.w + a1.w) + (a2.w + a3.w));
    float dv = dinv[vc];
    uint32 hv = *(const uint32*)(H + (size_t)vc * 64 + hl * 4);
    f32x2 dl = __builtin_amdgcn_cvt_pk_f32_fp8(hv, false);
    f32x2 dh = __builtin_amdgcn_cvt_pk_f32_fp8(hv, true);
    float4 bb = ((const float4*)bias)[hl];
    float sl = 2.f * dv * dv;
    float v0 = dv * acc.x + sl * dl[0] + bb.x;
    float v1 = dv * acc.y + sl * dl[1] + bb.y;
    float v2 = dv * acc.z + sl * dh[0] + bb.z;
    float v3 = dv * acc.w + sl * dh[1] + bb.w;
    // log_softmax across the 64 channels held by this 16-lane group
    float m = fmaxf(fmaxf(v0, v1), fmaxf(v2, v3));
    for (int o = 8; o > 0; o >>= 1) m = fmaxf(m, __shfl_xor(m, o));
    float e = (__expf(v0 - m) + __expf(v1 - m)) + (__expf(v2 - m) + __expf(v3 - m));
    for (int o = 8; o > 0; o >>= 1) e += __shfl_xor(e, o);
    float ls = m + __logf(e);
    if (valid)
        *(float4*)(out + (size_t)vc * 64 + hl * 4) =
            make_float4(v0 - ls, v1 - ls, v2 - ls, v3 - ls);
}

// ---------------- launch ----------------

extern "C" void kernel_launch(void* const* d_in, const int* in_sizes, int n_in,
                              void* d_out, int out_size, void* d_ws, size_t ws_size,
                              hipStream_t stream) {
    const float* x  = (const float*)d_in[0];
    const int*   ei = (const int*)d_in[1];
    const float* W1 = (const float*)d_in[2];
    const float* b1 = (const float*)d_in[3];
    const float* W2 = (const float*)d_in[4];
    const float* b2 = (const float*)d_in[5];
    float* out = (float*)d_out;

    const int N = in_sizes[0] / IN_CH;  // 100000
    const int E = in_sizes[1] / 2;      // 1600000
    const int* src = ei;
    const int* dst = ei + E;
    const int NB = (N + 255) >> BSH;    // 391 buckets

    char* w = (char*)d_ws;
    size_t off = 0;
    auto alloc = [&](size_t bytes) -> char* {
        char* p = w + off;
        off = (off + bytes + 255) & ~(size_t)255;
        return p;
    };
    int*   deg    = (int*)alloc((size_t)N * 4);
    int*   rowptr = (int*)alloc((size_t)N * 4);
    int*   bcnt   = (int*)alloc(512 * 4);
    int*   bbase  = (int*)alloc(513 * 4);
    int*   bcur   = (int*)alloc(512 * 4);
    float* dinv   = (float*)alloc((size_t)N * 4);
    int*   csr    = (int*)alloc((size_t)E * 4);
    unsigned short* W1t = (unsigned short*)alloc(128 * 128 * 2);
    unsigned short* W2t = (unsigned short*)alloc(64 * 128 * 2);
    uchar* H1  = (uchar*)alloc((size_t)N * HID_CH);          // fp8, 12.8 MB
    unsigned short* A1b = (unsigned short*)alloc((size_t)N * HID_CH * 2);  // bf16
    uchar* H2  = H1;                     // fp8; H1 dead after agg1
    int2*  pairBuf = (int2*)A1b;         // A1b not written until agg1 (after bucket_build)

    hipMemsetAsync(bcnt, 0, 512 * 4, stream);

    int gP = (E + PB - 1) / PB;         // 391 partition blocks

    bhist_wtrans<<<gP + 96, 256, 0, stream>>>(dst, bcnt, E, NB, gP, W1, W2, W1t, W2t);
    bscan<<<1, 512, 0, stream>>>(bcnt, bbase, bcur, NB, E);
    part1<<<gP, 256, 0, stream>>>(src, dst, bbase, bcur, pairBuf, E, NB);
    bucket_build<<<NB, 256, 0, stream>>>(pairBuf, bbase, rowptr, deg, dinv, csr, N);

    gemm_mfma<128, true><<<(N + 127) / 128, 256, 0, stream>>>(x, W1t, H1, N);
    agg_relu_128<<<(N + 15) / 16, 256, 0, stream>>>(H1, csr, rowptr, deg, dinv, b1, A1b, N);
    gemm_mfma<64, false><<<(N + 127) / 128, 256, 0, stream>>>(A1b, W2t, H2, N);
    agg_lsm_64<<<(N + 15) / 16, 256, 0, stream>>>(H2, csr, rowptr, deg, dinv, b2, out, N);
}